// Round 7
// baseline (1592.568 us; speedup 1.0000x reference)
//
#include <hip/hip_runtime.h>
#include <hip/hip_bf16.h>

#define DD 1024
#define HEADS 16
#define HDIM 64
#define NLAYER 4
#define FFDIM 4096
#define NVOCAB 32000
#define SEQ 1024

typedef __bf16 bf16_t;
typedef __bf16 bf16x8 __attribute__((ext_vector_type(8)));
typedef __bf16 bf16x4 __attribute__((ext_vector_type(4)));
typedef float f32x4 __attribute__((ext_vector_type(4)));

#define MFMA16(a, b, c) __builtin_amdgcn_mfma_f32_16x16x32_bf16((a), (b), (c), 0, 0, 0)

// async global->LDS, 16B per lane, dest = wave-uniform base + lane*16
#define GLD16(gp, lp) \
    __builtin_amdgcn_global_load_lds( \
        (const __attribute__((address_space(1))) void*)(gp), \
        (__attribute__((address_space(3))) void*)(lp), 16, 0, 0)

static __device__ __forceinline__ bf16x8 pack8(float4 u, float4 v) {
    bf16x8 r;
    r[0] = (bf16_t)u.x; r[1] = (bf16_t)u.y; r[2] = (bf16_t)u.z; r[3] = (bf16_t)u.w;
    r[4] = (bf16_t)v.x; r[5] = (bf16_t)v.y; r[6] = (bf16_t)v.z; r[7] = (bf16_t)v.w;
    return r;
}

// ---------------------------------------------------------------------------
// f32 -> bf16 bulk convert (weights, once per launch). n % 2048 == 0.
// ---------------------------------------------------------------------------
__global__ __launch_bounds__(256) void cvt_kernel(
    const float* __restrict__ src, bf16_t* __restrict__ dst, long n)
{
    long i = ((long)blockIdx.x * 256 + threadIdx.x) * 8;
    if (i < n) {
        float4 a = *(const float4*)(src + i);
        float4 b = *(const float4*)(src + i + 4);
        *(bf16x8*)(dst + i) = pack8(a, b);
    }
}

// ---------------------------------------------------------------------------
// Head-rope cos/sin tables: [S][32]
// ---------------------------------------------------------------------------
__global__ __launch_bounds__(256) void ropetab_kernel(
    const float* __restrict__ inv_freq, const float* __restrict__ rbias,
    float* __restrict__ ctab, float* __restrict__ stab)
{
    int idx = blockIdx.x * 256 + threadIdx.x;     // s*32 + i
    int s = idx >> 5, i = idx & 31;
    float fr = (float)s * inv_freq[i] + rbias[idx];
    ctab[idx] = cosf(fr);
    stab[idx] = sinf(fr);
}

// ---------------------------------------------------------------------------
// Embedding + decoder-level rotary
// ---------------------------------------------------------------------------
__global__ __launch_bounds__(512) void embed_rope_kernel(
    const int* __restrict__ x, const float* __restrict__ tok_emb,
    const float* __restrict__ pos_emb, const float* __restrict__ inv_freq,
    const float* __restrict__ rbias, float* __restrict__ h, int S)
{
    const int row = blockIdx.x;      // b*S + s
    const int s = row % S;
    const int i = threadIdx.x;       // 0..511 pair index
    const int tok = x[row];
    const float* e = tok_emb + (size_t)tok * DD;
    const float* p = pos_emb + (size_t)s * DD;
    float a = e[2*i]   + p[2*i];
    float b = e[2*i+1] + p[2*i+1];
    float fr = (float)s * inv_freq[i] + rbias[(size_t)s * (DD/2) + i];
    float c = cosf(fr), sn = sinf(fr);
    h[(size_t)row*DD + 2*i]   = a*c - b*sn;
    h[(size_t)row*DD + 2*i+1] = a*sn + b*c;
}

// ---------------------------------------------------------------------------
// RMSNorm with bf16 output
// ---------------------------------------------------------------------------
__global__ __launch_bounds__(256) void rmsnorm_kernel(
    const float* __restrict__ x, const float* __restrict__ w,
    bf16_t* __restrict__ y)
{
    const int row = blockIdx.x;
    const float* xr = x + (size_t)row * DD;
    float ss = 0.f;
    for (int j = threadIdx.x; j < DD; j += 256) { float v = xr[j]; ss += v*v; }
    for (int off = 32; off > 0; off >>= 1) ss += __shfl_down(ss, off, 64);
    __shared__ float r[4];
    if ((threadIdx.x & 63) == 0) r[threadIdx.x >> 6] = ss;
    __syncthreads();
    float tot = r[0] + r[1] + r[2] + r[3];
    float sc = rsqrtf(tot * (1.0f/(float)DD) + 1e-8f);
    for (int j = threadIdx.x; j < DD; j += 256)
        y[(size_t)row*DD + j] = (bf16_t)(xr[j] * sc * w[j]);
}

// ---------------------------------------------------------------------------
// V tile-suffix sums: vsuf[bh][t][d] = sum_{k >= 128t} Vt[bh][d][k], t=1..7
// 256 threads: (d = tid&63, k-quarter = tid>>6), bf16x8 vector reads.
// ---------------------------------------------------------------------------
__global__ __launch_bounds__(256) void vsuf_kernel(
    const bf16_t* __restrict__ Vt, float* __restrict__ vsuf, int S)
{
    __shared__ float part[4][7][64];
    const int d = threadIdx.x & 63, s4 = threadIdx.x >> 6;
    const int bh = blockIdx.x;
    const bf16_t* vp = Vt + ((size_t)bh*HDIM + d)*S;
    for (int t = 1; t <= 7; ++t) {
        float a = 0.f;
        const bf16_t* p = vp + t*128 + s4*32;
        #pragma unroll
        for (int c = 0; c < 4; ++c) {
            bf16x8 v = *(const bf16x8*)(p + c*8);
            #pragma unroll
            for (int e = 0; e < 8; ++e) a += (float)v[e];
        }
        part[s4][t-1][d] = a;
    }
    __syncthreads();
    if (s4 == 0) {
        float acc2 = 0.f;
        for (int t = 7; t >= 1; --t) {
            acc2 += part[0][t-1][d] + part[1][t-1][d] + part[2][t-1][d] + part[3][t-1][d];
            vsuf[((size_t)bh*8 + t)*64 + d] = acc2;
        }
    }
}

// ---------------------------------------------------------------------------
// bf16 MFMA GEMM, reg-prefetch schedule (unchanged from round 6).
// ---------------------------------------------------------------------------
__global__ __launch_bounds__(256) void gemm_bf(
    const bf16_t* __restrict__ A, const bf16_t* __restrict__ W,
    const float* __restrict__ bias, const float* __restrict__ add1,
    const float* __restrict__ add2, float* __restrict__ C,
    bf16_t* __restrict__ Cb,
    int M, int N, int K, int relu, int mode, int swz)
{
    __shared__ __align__(16) bf16_t As[128*64];
    __shared__ __align__(16) bf16_t Bs[128*64];
    const int tid = threadIdx.x;
    int bx = blockIdx.x, by = blockIdx.y;
    if (swz) {
        const int nbx = gridDim.x, nby = gridDim.y;
        const int nwg = nbx * nby;             // divisible by 8
        const int lin = by * nbx + bx;
        const int wg  = (lin & 7) * (nwg >> 3) + (lin >> 3);
        bx = wg / nby;                         // n-major: same-n blocks adjacent
        by = wg % nby;
    }
    const int m0 = by * 128, n0 = bx * 128;
    const int l = tid & 63, w = tid >> 6;
    const int wr = (w >> 1) * 64, wc = (w & 1) * 64;
    const int lr = l & 15, lk = (l >> 4) * 8;

    const int srow = l >> 3, scol = (l & 7) * 8;
    const bf16_t* Ag = A + (size_t)(m0 + w*32 + srow) * K + scol;
    const bf16_t* Wg = W + (size_t)(n0 + w*32 + srow) * K + scol;

    f32x4 z4 = {0.f, 0.f, 0.f, 0.f};
    f32x4 acc[4][4];
    #pragma unroll
    for (int i = 0; i < 4; ++i)
        #pragma unroll
        for (int j = 0; j < 4; ++j) acc[i][j] = z4;

    #pragma unroll
    for (int it = 0; it < 4; ++it) {
        GLD16(Ag + (size_t)(it*8)*K, As + (w*4 + it)*512);
        GLD16(Wg + (size_t)(it*8)*K, Bs + (w*4 + it)*512);
    }

    for (int k0 = 0; k0 < K; k0 += 64) {
        __syncthreads();                       // B1: tile landed
        bf16x8 afr[8], bfr[8];
        #pragma unroll
        for (int kk = 0; kk < 2; ++kk)
            #pragma unroll
            for (int i = 0; i < 4; ++i) {
                afr[kk*4+i] = *(const bf16x8*)&As[(wr + i*16 + lr)*64 + kk*32 + lk];
                bfr[kk*4+i] = *(const bf16x8*)&Bs[(wc + i*16 + lr)*64 + kk*32 + lk];
            }
        __syncthreads();                       // B2: reads done, LDS free
        if (k0 + 64 < K) {
            #pragma unroll
            for (int it = 0; it < 4; ++it) {
                GLD16(Ag + (size_t)(it*8)*K + k0 + 64, As + (w*4 + it)*512);
                GLD16(Wg + (size_t)(it*8)*K + k0 + 64, Bs + (w*4 + it)*512);
            }
        }
        #pragma unroll
        for (int kk = 0; kk < 2; ++kk)
            #pragma unroll
            for (int i = 0; i < 4; ++i)
                #pragma unroll
                for (int j = 0; j < 4; ++j)
                    acc[i][j] = MFMA16(afr[kk*4+i], bfr[kk*4+j], acc[i][j]);
    }

    #pragma unroll
    for (int i = 0; i < 4; ++i) {
        #pragma unroll
        for (int j = 0; j < 4; ++j) {
            const int col  = n0 + wc + j*16 + lr;
            const int row0 = m0 + wr + i*16 + (l >> 4)*4;
            const float bv = bias ? bias[col] : 0.f;
            #pragma unroll
            for (int r2 = 0; r2 < 4; ++r2) {
                const int row = row0 + r2;
                float val = acc[i][j][r2] + bv;
                if (add1) val += add1[(size_t)row*N + col];
                if (add2) val += add2[(size_t)row*N + col];
                if (relu) val = fmaxf(val, 0.f);
                if (mode == 0) C[(size_t)row*N + col] = val;
                else           Cb[(size_t)row*N + col] = (bf16_t)val;
            }
        }
    }
}

// ---------------------------------------------------------------------------
// Fallback logits GEMM (A bf16 via gload_lds, W f32 reg-staged). Unchanged.
// ---------------------------------------------------------------------------
__global__ __launch_bounds__(256) void gemm_bfw32(
    const bf16_t* __restrict__ A, const float* __restrict__ W,
    float* __restrict__ C, int M, int N, int K)
{
    __shared__ __align__(16) bf16_t As[128*64];
    __shared__ __align__(16) bf16_t Bs[128*64];
    const int tid = threadIdx.x;
    const int m0 = blockIdx.y * 128, n0 = blockIdx.x * 128;
    const int l = tid & 63, w = tid >> 6;
    const int wr = (w >> 1) * 64, wc = (w & 1) * 64;
    const int lr = l & 15, lk = (l >> 4) * 8;
    const int srow = l >> 3, scol = (l & 7) * 8;
    const bf16_t* Ag = A + (size_t)(m0 + w*32 + srow) * K + scol;
    const int r = tid >> 1, half = (tid & 1) * 32;
    const float* Wp = W + (size_t)(n0 + r) * K + half;

    f32x4 z4 = {0.f, 0.f, 0.f, 0.f};
    f32x4 acc[4][4];
    #pragma unroll
    for (int i = 0; i < 4; ++i)
        #pragma unroll
        for (int j = 0; j < 4; ++j) acc[i][j] = z4;

    for (int k0 = 0; k0 < K; k0 += 64) {
        float4 wv[8];
        #pragma unroll
        for (int j = 0; j < 8; ++j) wv[j] = *(const float4*)(Wp + k0 + 4*j);
        __syncthreads();
        #pragma unroll
        for (int it = 0; it < 4; ++it)
            GLD16(Ag + (size_t)(it*8)*K + k0, As + (w*4 + it)*512);
        #pragma unroll
        for (int j = 0; j < 4; ++j)
            *(bf16x8*)&Bs[r*64 + half + 8*j] = pack8(wv[2*j], wv[2*j+1]);
        __syncthreads();
        #pragma unroll
        for (int kk = 0; kk < 2; ++kk) {
            bf16x8 afr[4], bfr[4];
            #pragma unroll
            for (int i = 0; i < 4; ++i)
                afr[i] = *(const bf16x8*)&As[(wr + i*16 + lr)*64 + kk*32 + lk];
            #pragma unroll
            for (int j = 0; j < 4; ++j)
                bfr[j] = *(const bf16x8*)&Bs[(wc + j*16 + lr)*64 + kk*32 + lk];
            #pragma unroll
            for (int i = 0; i < 4; ++i)
                #pragma unroll
                for (int j = 0; j < 4; ++j)
                    acc[i][j] = MFMA16(afr[i], bfr[j], acc[i][j]);
        }
    }
    #pragma unroll
    for (int i = 0; i < 4; ++i)
        #pragma unroll
        for (int j = 0; j < 4; ++j) {
            const int col  = n0 + wc + j*16 + lr;
            const int row0 = m0 + wr + i*16 + (l >> 4)*4;
            #pragma unroll
            for (int r2 = 0; r2 < 4; ++r2)
                C[(size_t)(row0 + r2)*N + col] = acc[i][j][r2];
        }
}

// ---------------------------------------------------------------------------
// Fused QKV GEMM (unchanged from round 6).
// ---------------------------------------------------------------------------
__global__ __launch_bounds__(256) void qkv_gemm(
    const bf16_t* __restrict__ A, const bf16_t* __restrict__ Wq,
    const bf16_t* __restrict__ Wk, const bf16_t* __restrict__ Wv,
    const float* __restrict__ qb, const float* __restrict__ vbias,
    const float* __restrict__ ctab, const float* __restrict__ stab,
    const float* __restrict__ fptr,
    bf16_t* __restrict__ qbf, bf16_t* __restrict__ kbf,
    bf16_t* __restrict__ vt, float* __restrict__ zmult, int S)
{
    __shared__ __align__(16) bf16_t As[128*64];
    __shared__ __align__(16) bf16_t Bs[128*64];
    const int tid = threadIdx.x;
    const int seg = blockIdx.x >> 3;              // 0=q 1=k 2=v
    const int n0  = (blockIdx.x & 7) * 128;       // col within segment
    const int m0  = blockIdx.y * 128;
    const bf16_t* W = (seg == 0) ? Wq : (seg == 1) ? Wk : Wv;
    const int K = DD;
    const int l = tid & 63, w = tid >> 6;
    const int wr = (w >> 1) * 64, wc = (w & 1) * 64;
    const int lr = l & 15, lk = (l >> 4) * 8;

    const int srow = l >> 3, scol = (l & 7) * 8;
    const bf16_t* Ag = A + (size_t)(m0 + w*32 + srow) * K + scol;
    const bf16_t* Wg = W + (size_t)(n0 + w*32 + srow) * K + scol;

    f32x4 z4 = {0.f, 0.f, 0.f, 0.f};
    f32x4 acc[4][4];
    #pragma unroll
    for (int i = 0; i < 4; ++i)
        #pragma unroll
        for (int j = 0; j < 4; ++j) acc[i][j] = z4;

    #pragma unroll
    for (int it = 0; it < 4; ++it) {
        GLD16(Ag + (size_t)(it*8)*K, As + (w*4 + it)*512);
        GLD16(Wg + (size_t)(it*8)*K, Bs + (w*4 + it)*512);
    }

    for (int k0 = 0; k0 < K; k0 += 64) {
        __syncthreads();
        bf16x8 afr[8], bfr[8];
        #pragma unroll
        for (int kk = 0; kk < 2; ++kk)
            #pragma unroll
            for (int i = 0; i < 4; ++i) {
                afr[kk*4+i] = *(const bf16x8*)&As[(wr + i*16 + lr)*64 + kk*32 + lk];
                bfr[kk*4+i] = *(const bf16x8*)&Bs[(wc + i*16 + lr)*64 + kk*32 + lk];
            }
        __syncthreads();
        if (k0 + 64 < K) {
            #pragma unroll
            for (int it = 0; it < 4; ++it) {
                GLD16(Ag + (size_t)(it*8)*K + k0 + 64, As + (w*4 + it)*512);
                GLD16(Wg + (size_t)(it*8)*K + k0 + 64, Bs + (w*4 + it)*512);
            }
        }
        #pragma unroll
        for (int kk = 0; kk < 2; ++kk)
            #pragma unroll
            for (int i = 0; i < 4; ++i)
                #pragma unroll
                for (int j = 0; j < 4; ++j)
                    acc[i][j] = MFMA16(afr[kk*4+i], bfr[kk*4+j], acc[i][j]);
    }

    float zf = 0.f;
    if (seg == 1) {
        float f = fptr[0];
        float sp = (f > 20.f) ? f : log1pf(expf(f));
        zf = fminf(fmaxf(sp, 1e-5f), 0.1f);
    }

    #pragma unroll
    for (int i = 0; i < 4; ++i) {
        #pragma unroll
        for (int j = 0; j < 4; ++j) {
            const int col = n0 + wc + j*16 + lr;          // 0..1023 within seg
            const float bv = (seg == 0) ? qb[col] : (seg == 2) ? vbias[col] : 0.f;
            const int d  = col & 63;
            const int hh = col >> 6;
            const int pi = d >> 1;
            #pragma unroll
            for (int r2 = 0; r2 < 4; ++r2) {
                const int row = m0 + wr + i*16 + (l >> 4)*4 + r2;
                const int s  = row & (SEQ - 1);
                const int bb = row >> 10;
                float val = acc[i][j][r2] + bv;
                if (seg < 2) {
                    float partner = __shfl_xor(val, 1, 64);
                    float c  = ctab[s*32 + pi];
                    float sn = stab[s*32 + pi];
                    float out = ((d & 1) == 0) ? (val*c - partner*sn)
                                               : (partner*sn + val*c);
                    if (seg == 0) {
                        qbf[(size_t)row*DD + col] = (bf16_t)out;
                    } else {
                        kbf[(size_t)row*DD + col] = (bf16_t)out;
                        if (d == 0)
                            zmult[(size_t)(bb*HEADS + hh)*S + s] =
                                (out == 0.0f) ? zf : 1.0f;
                    }
                } else {
                    vt[((size_t)(bb*HEADS + hh)*HDIM + d)*SEQ + s] = (bf16_t)val;
                }
            }
        }
    }
}

// ---------------------------------------------------------------------------
// Fused flash attention: per (64-q-row tile, bh) block, 4 waves (16 q each).
// Swapped QK^T (mfma(K,Q)): lane l holds S[k = f*16 + (l>>4)*4 + r][q = l&15]
// -> P packs as bf16x4 (4 consecutive k) -> ds_write_b64 into XOR-swizzled Ps.
// Online softmax in regs (stats at q=l&15; shfl-broadcast for rescale).
// Causal tail added analytically via vsuf (masked scores are exact zeros in
// the reference's mask-by-zero softmax). PV: mfma(P_frag, Vt_frag).
// Ps is written and read only by the owning wave -> no extra barrier.
// ---------------------------------------------------------------------------
__global__ __launch_bounds__(256) void attn_fused(
    const bf16_t* __restrict__ qbf, const bf16_t* __restrict__ kbf,
    const bf16_t* __restrict__ Vt, const float* __restrict__ zmult,
    const float* __restrict__ vsuf, bf16_t* __restrict__ O, int S)
{
    __shared__ __align__(16) bf16_t Ks[128*64];   // [k][64]
    __shared__ __align__(16) bf16_t Vs[64*128];   // [d][128]
    __shared__ __align__(16) bf16_t Ps[64*128];   // [q][128], XOR-swizzled

    const int tid = threadIdx.x;
    const int qt = (gridDim.x - 1) - blockIdx.x;  // heavy tiles dispatch first
    const int q0 = qt * 64;
    const int bh = blockIdx.y, b = bh >> 4, hh = bh & 15;
    const int l = tid & 63, w = tid >> 6;
    const int lr = l & 15, g = l >> 4;
    const int lk = g * 8;
    const int ktm = q0 >> 7;                 // last causal 128-key tile
    const int cnt = S - 128*(ktm + 1);       // fully-masked tail key count
    const int myq = q0 + w*16 + lr;          // q this lane holds stats for
    const int qloc = w*16 + lr;              // row in Ps

    bf16x8 qfr[2];
    {
        const bf16_t* qp = qbf + (size_t)(b*S + myq)*DD + hh*HDIM;
        qfr[0] = *(const bf16x8*)(qp + lk);
        qfr[1] = *(const bf16x8*)(qp + 32 + lk);
    }

    float m_run = (cnt > 0) ? 0.f : -3.0e38f;   // masked zeros participate
    float psum = 0.f;
    f32x4 z4 = {0.f, 0.f, 0.f, 0.f};
    f32x4 acc[4];                  // O[q = w*16 + g*4+r][d = j*16+lr]
    #pragma unroll
    for (int j = 0; j < 4; ++j) acc[j] = z4;

    const int sr = l >> 3, sc = (l & 7) * 8;

    for (int kt = 0; kt <= ktm; ++kt) {
        __syncthreads();                       // Ks/Vs free from prev iter
        const bf16_t* Kg = kbf + (size_t)(b*S + kt*128)*DD + hh*HDIM;
        #pragma unroll
        for (int it = 0; it < 4; ++it) {
            const int krow = (w*4 + it)*8 + sr;
            GLD16(Kg + (size_t)krow*DD + sc, Ks + (w*4 + it)*512);
        }
        const bf16_t* Vg = Vt + ((size_t)bh*HDIM)*S + kt*128;
        #pragma unroll
        for (int it = 0; it < 4; ++it) {
            const int drow = (w*4 + it)*4 + g;
            GLD16(Vg + (size_t)drow*S + lr*8, Vs + (w*4 + it)*512);
        }
        __syncthreads();                       // tiles staged (vmcnt drained)

        // QK^T: A = K rows -> C rows = k; B = Q rows -> C cols = q
        float sv[8][4];
        float mtile = -3.0e38f;
        #pragma unroll
        for (int f = 0; f < 8; ++f) {
            bf16x8 ka0 = *(const bf16x8*)&Ks[(f*16 + lr)*64 + lk];
            bf16x8 ka1 = *(const bf16x8*)&Ks[(f*16 + lr)*64 + 32 + lk];
            f32x4 t = z4;
            t = MFMA16(ka0, qfr[0], t);
            t = MFMA16(ka1, qfr[1], t);
            #pragma unroll
            for (int r = 0; r < 4; ++r) {
                const int key = kt*128 + f*16 + g*4 + r;
                float v = t[r] * 0.125f;       // HD^-0.5
                v = (key <= myq) ? v * zmult[(size_t)bh*S + key] : 0.f;
                sv[f][r] = v;
                mtile = fmaxf(mtile, v);
            }
        }
        mtile = fmaxf(mtile, __shfl_xor(mtile, 16, 64));
        mtile = fmaxf(mtile, __shfl_xor(mtile, 32, 64));
        const float m_new = fmaxf(m_run, mtile);
        const float fac = expf(m_run - m_new);
        m_run = m_new;

        float ps_t = 0.f;
        #pragma unroll
        for (int f = 0; f < 8; ++f) {
            bf16x4 pk;
            #pragma unroll
            for (int r = 0; r < 4; ++r) {
                float p = expf(sv[f][r] - m_new);
                ps_t += p;
                pk[r] = (bf16_t)p;
            }
            const int byteoff = (qloc*256 + f*32 + g*8) ^ ((lr & 7) << 4);
            *(bf16x4*)((char*)Ps + byteoff) = pk;
        }
        ps_t += __shfl_xor(ps_t, 16, 64);
        ps_t += __shfl_xor(ps_t, 32, 64);
        psum = psum * fac + ps_t;

        #pragma unroll
        for (int r = 0; r < 4; ++r) {
            const float fr_ = __shfl(fac, g*4 + r, 64);
            #pragma unroll
            for (int j = 0; j < 4; ++j) acc[j][r] *= fr_;
        }

        #pragma unroll
        for (int kk = 0; kk < 4; ++kk) {
            const int rboff = (qloc*256 + kk*64 + g*16) ^ ((lr & 7) << 4);
            bf16x8 pa = *(const bf16x8*)((char*)Ps + rboff);
            #pragma unroll
            for (int j = 0; j < 4; ++j) {
                bf16x8 vb = *(const bf16x8*)&Vs[(j*16 + lr)*128 + kk*32 + lk];
                acc[j] = MFMA16(pa, vb, acc[j]);
            }
        }
    }

    if (cnt > 0) psum += (float)cnt * expf(-m_run);

    #pragma unroll
    for (int r = 0; r < 4; ++r) {
        const float m_r  = __shfl(m_run, g*4 + r, 64);
        const float ps_r = __shfl(psum,  g*4 + r, 64);
        const float inv = 1.0f / ps_r;
        const float tailf = (cnt > 0) ? expf(-m_r) : 0.f;
        const int qrow = q0 + w*16 + g*4 + r;
        const size_t rowbase = (size_t)(b*S + qrow)*DD + hh*HDIM;
        #pragma unroll
        for (int j = 0; j < 4; ++j) {
            float val = acc[j][r];
            if (cnt > 0)
                val += tailf * vsuf[((size_t)bh*8 + ktm + 1)*64 + j*16 + lr];
            O[rowbase + j*16 + lr] = (bf16_t)(val * inv);
        }
    }
}

// ---------------------------------------------------------------------------
extern "C" void kernel_launch(void* const* d_in, const int* in_sizes, int n_in,
                              void* d_out, int out_size, void* d_ws, size_t ws_size,
                              hipStream_t stream)
{
    const int S = SEQ;
    const int B = in_sizes[0] / S;     // 2
    const int M = B * S;               // 2048
    const int BH = B * HEADS;          // 32

    const int*   x       = (const int*)  d_in[0];
    const float* tok_emb = (const float*)d_in[2];
    const float* pos_emb = (const float*)d_in[3];
    const float* rif     = (const float*)d_in[4];
    const float* rbias   = (const float*)d_in[5];
    const float* brif    = (const float*)d_in[6];
    const float* bbias   = (const float*)d_in[7];
    const float* lna     = (const float*)d_in[8];
    const float* qw      = (const float*)d_in[9];
    const float* qb      = (const float*)d_in[10];
    const float* kw      = (const float*)d_in[11];
    const float* vw      = (const float*)d_in[12];
    const float* vbias   = (const float*)d_in[13];
    const float* ow      = (const float*)d_in[14];
    const float* ob      = (const float*)d_in[15];
    const float* factor  = (const float*)d_in[16];
    const float* lnc     = (const float*)d_in[17];
    const float* w1      = (const float*)d_in[18];
    const float* b1      = (const float*)d_in[19];
    const float* w2      = (const float*)d_in[20];
    const float* b2      = (const float*)d_in[21];
    const float* lnd     = (const float*)d_in[22];

    char* ob_ = (char*)d_out;
    const size_t MiB = 1024*1024;
    float*  h      = (float*)(ob_ + 0*MiB);      // 8 MiB
    float*  h2     = (float*)(ob_ + 8*MiB);      // 8 MiB
    bf16_t* qbf    = (bf16_t*)(ob_ + 16*MiB);    // 4 MiB
    bf16_t* kbf    = (bf16_t*)(ob_ + 20*MiB);    // 4 MiB
    bf16_t* vt     = (bf16_t*)(ob_ + 24*MiB);    // 4 MiB  Vt[b][h][d][S]
    bf16_t* attno  = (bf16_t*)(ob_ + 28*MiB);    // 4 MiB
    bf16_t* m1     = (bf16_t*)(ob_ + 32*MiB);    // 16 MiB
    float*  zmult  = (float*)(ob_ + 48*MiB);     // 128 KiB
    float*  ctab   = (float*)(ob_ + 50*MiB);     // 128 KiB
    float*  stab   = (float*)(ob_ + 51*MiB);     // 128 KiB
    float*  vsuf   = (float*)(ob_ + 52*MiB);     // 64 KiB
    bf16_t* qw_bf  = (bf16_t*)(ob_ + 64*MiB);    // 8 MiB (4 layers)
    bf16_t* kw_bf  = (bf16_t*)(ob_ + 72*MiB);
    bf16_t* vw_bf  = (bf16_t*)(ob_ + 80*MiB);
    bf16_t* ow_bf  = (bf16_t*)(ob_ + 88*MiB);
    bf16_t* w1_bf  = (bf16_t*)(ob_ + 96*MiB);    // 32 MiB
    bf16_t* w2_bf  = (bf16_t*)(ob_ + 128*MiB);   // 32 MiB -> ends 160 < 250 MiB

    bf16_t* hn      = (bf16_t*)d_ws;             // 4 MiB
    bf16_t* temb_bf = (bf16_t*)((char*)d_ws + 4*MiB);
    const bool big_ws = ws_size >= (size_t)(70*MiB);

    const long NW_D = (long)NLAYER * DD * DD;
    const long NW_F = (long)NLAYER * FFDIM * DD;
    const long NW_E = (long)NVOCAB * DD;
    cvt_kernel<<<NW_D/2048, 256, 0, stream>>>(qw, qw_bf, NW_D);
    cvt_kernel<<<NW_D/2048, 256, 0, stream>>>(kw, kw_bf, NW_D);
    cvt_kernel<<<NW_D/2048, 256, 0, stream>>>(vw, vw_bf, NW_D);
    cvt_kernel<<<NW_D/2048, 256, 0, stream>>>(ow, ow_bf, NW_D);
    cvt_kernel<<<NW_F/2048, 256, 0, stream>>>(w1, w1_bf, NW_F);
    cvt_kernel<<<NW_F/2048, 256, 0, stream>>>(w2, w2_bf, NW_F);
    if (big_ws)
        cvt_kernel<<<(NW_E+2047)/2048, 256, 0, stream>>>(tok_emb, temb_bf, NW_E);
    ropetab_kernel<<<(S*32)/256, 256, 0, stream>>>(brif, bbias, ctab, stab);

    dim3 gD(DD/128,     M/128);
    dim3 gF(FFDIM/128,  M/128);
    dim3 gV(NVOCAB/128, M/128);
    dim3 gQKV(3*DD/128, M/128);
    dim3 gATT(S/64, BH);

    embed_rope_kernel<<<M, 512, 0, stream>>>(x, tok_emb, pos_emb, rif, rbias, h, S);

    for (int l = 0; l < NLAYER; ++l) {
        const size_t wo = (size_t)l * DD * DD;
        const size_t fo = (size_t)l * FFDIM * DD;
        rmsnorm_kernel<<<M, 256, 0, stream>>>(h, lna + l*DD, hn);
        qkv_gemm<<<gQKV, 256, 0, stream>>>(hn, qw_bf + wo, kw_bf + wo, vw_bf + wo,
                                           qb + l*DD, vbias + l*DD, ctab, stab,
                                           factor + l, qbf, kbf, vt, zmult, S);
        vsuf_kernel<<<BH, 256, 0, stream>>>(vt, vsuf, S);
        attn_fused<<<gATT, 256, 0, stream>>>(qbf, kbf, vt, zmult, vsuf, attno, S);
        // h2 = attno @ ow^T + ob + h
        gemm_bf<<<gD, 256, 0, stream>>>(attno, ow_bf + wo, ob + l*DD, h, nullptr,
                                        h2, nullptr, M, DD, DD, 0, 0, 0);
        rmsnorm_kernel<<<M, 256, 0, stream>>>(h2, lnc + l*DD, hn);
        gemm_bf<<<gF, 256, 0, stream>>>(hn, w1_bf + fo, b1 + l*FFDIM, nullptr, nullptr,
                                        nullptr, m1, M, FFDIM, DD, 1, 1, 0);
        // h_new = m1 @ w2^T + b2 + h2 + h   (== 2*h_old + attn + mlp)
        gemm_bf<<<gD, 256, 0, stream>>>(m1, w2_bf + fo, b2 + l*DD, h2, h,
                                        h, nullptr, M, DD, FFDIM, 0, 0, 0);
    }

    rmsnorm_kernel<<<M, 256, 0, stream>>>(h, lnd, hn);
    if (big_ws)
        gemm_bf<<<gV, 256, 0, stream>>>(hn, temb_bf, nullptr, nullptr, nullptr,
                                        (float*)d_out, nullptr, M, NVOCAB, DD, 0, 0, 1);
    else
        gemm_bfw32<<<gV, 256, 0, stream>>>(hn, tok_emb, (float*)d_out, M, NVOCAB, DD);
}

// Round 8
// 1465.980 us; speedup vs baseline: 1.0864x; 1.0864x over previous
//
#include <hip/hip_runtime.h>
#include <hip/hip_bf16.h>

#define DD 1024
#define HEADS 16
#define HDIM 64
#define NLAYER 4
#define FFDIM 4096
#define NVOCAB 32000
#define SEQ 1024

typedef __bf16 bf16_t;
typedef __bf16 bf16x8 __attribute__((ext_vector_type(8)));
typedef __bf16 bf16x4 __attribute__((ext_vector_type(4)));
typedef float f32x4 __attribute__((ext_vector_type(4)));

#define MFMA16(a, b, c) __builtin_amdgcn_mfma_f32_16x16x32_bf16((a), (b), (c), 0, 0, 0)

// async global->LDS, 16B per lane, dest = wave-uniform base + lane*16
#define GLD16(gp, lp) \
    __builtin_amdgcn_global_load_lds( \
        (const __attribute__((address_space(1))) void*)(gp), \
        (__attribute__((address_space(3))) void*)(lp), 16, 0, 0)

static __device__ __forceinline__ bf16x8 pack8(float4 u, float4 v) {
    bf16x8 r;
    r[0] = (bf16_t)u.x; r[1] = (bf16_t)u.y; r[2] = (bf16_t)u.z; r[3] = (bf16_t)u.w;
    r[4] = (bf16_t)v.x; r[5] = (bf16_t)v.y; r[6] = (bf16_t)v.z; r[7] = (bf16_t)v.w;
    return r;
}

// ---------------------------------------------------------------------------
// f32 -> bf16 bulk convert (weights, once per launch). n % 2048 == 0.
// ---------------------------------------------------------------------------
__global__ __launch_bounds__(256) void cvt_kernel(
    const float* __restrict__ src, bf16_t* __restrict__ dst, long n)
{
    long i = ((long)blockIdx.x * 256 + threadIdx.x) * 8;
    if (i < n) {
        float4 a = *(const float4*)(src + i);
        float4 b = *(const float4*)(src + i + 4);
        *(bf16x8*)(dst + i) = pack8(a, b);
    }
}

// ---------------------------------------------------------------------------
// Head-rope cos/sin tables: [S][32]
// ---------------------------------------------------------------------------
__global__ __launch_bounds__(256) void ropetab_kernel(
    const float* __restrict__ inv_freq, const float* __restrict__ rbias,
    float* __restrict__ ctab, float* __restrict__ stab)
{
    int idx = blockIdx.x * 256 + threadIdx.x;     // s*32 + i
    int s = idx >> 5, i = idx & 31;
    float fr = (float)s * inv_freq[i] + rbias[idx];
    ctab[idx] = cosf(fr);
    stab[idx] = sinf(fr);
}

// ---------------------------------------------------------------------------
// Embedding + decoder-level rotary
// ---------------------------------------------------------------------------
__global__ __launch_bounds__(512) void embed_rope_kernel(
    const int* __restrict__ x, const float* __restrict__ tok_emb,
    const float* __restrict__ pos_emb, const float* __restrict__ inv_freq,
    const float* __restrict__ rbias, float* __restrict__ h, int S)
{
    const int row = blockIdx.x;      // b*S + s
    const int s = row % S;
    const int i = threadIdx.x;       // 0..511 pair index
    const int tok = x[row];
    const float* e = tok_emb + (size_t)tok * DD;
    const float* p = pos_emb + (size_t)s * DD;
    float a = e[2*i]   + p[2*i];
    float b = e[2*i+1] + p[2*i+1];
    float fr = (float)s * inv_freq[i] + rbias[(size_t)s * (DD/2) + i];
    float c = cosf(fr), sn = sinf(fr);
    h[(size_t)row*DD + 2*i]   = a*c - b*sn;
    h[(size_t)row*DD + 2*i+1] = a*sn + b*c;
}

// ---------------------------------------------------------------------------
// RMSNorm with bf16 output
// ---------------------------------------------------------------------------
__global__ __launch_bounds__(256) void rmsnorm_kernel(
    const float* __restrict__ x, const float* __restrict__ w,
    bf16_t* __restrict__ y)
{
    const int row = blockIdx.x;
    const float* xr = x + (size_t)row * DD;
    float ss = 0.f;
    for (int j = threadIdx.x; j < DD; j += 256) { float v = xr[j]; ss += v*v; }
    for (int off = 32; off > 0; off >>= 1) ss += __shfl_down(ss, off, 64);
    __shared__ float r[4];
    if ((threadIdx.x & 63) == 0) r[threadIdx.x >> 6] = ss;
    __syncthreads();
    float tot = r[0] + r[1] + r[2] + r[3];
    float sc = rsqrtf(tot * (1.0f/(float)DD) + 1e-8f);
    for (int j = threadIdx.x; j < DD; j += 256)
        y[(size_t)row*DD + j] = (bf16_t)(xr[j] * sc * w[j]);
}

// ---------------------------------------------------------------------------
// V tile-suffix sums: vsuf[bh][t][d] = sum_{k >= 128t} Vt[bh][d][k], t=1..7
// ---------------------------------------------------------------------------
__global__ __launch_bounds__(256) void vsuf_kernel(
    const bf16_t* __restrict__ Vt, float* __restrict__ vsuf, int S)
{
    __shared__ float part[4][7][64];
    const int d = threadIdx.x & 63, s4 = threadIdx.x >> 6;
    const int bh = blockIdx.x;
    const bf16_t* vp = Vt + ((size_t)bh*HDIM + d)*S;
    for (int t = 1; t <= 7; ++t) {
        float a = 0.f;
        const bf16_t* p = vp + t*128 + s4*32;
        #pragma unroll
        for (int c = 0; c < 4; ++c) {
            bf16x8 v = *(const bf16x8*)(p + c*8);
            #pragma unroll
            for (int e = 0; e < 8; ++e) a += (float)v[e];
        }
        part[s4][t-1][d] = a;
    }
    __syncthreads();
    if (s4 == 0) {
        float acc2 = 0.f;
        for (int t = 7; t >= 1; --t) {
            acc2 += part[0][t-1][d] + part[1][t-1][d] + part[2][t-1][d] + part[3][t-1][d];
            vsuf[((size_t)bh*8 + t)*64 + d] = acc2;
        }
    }
}

// ---------------------------------------------------------------------------
// bf16 MFMA GEMM, reg-prefetch schedule (unchanged).
// ---------------------------------------------------------------------------
__global__ __launch_bounds__(256) void gemm_bf(
    const bf16_t* __restrict__ A, const bf16_t* __restrict__ W,
    const float* __restrict__ bias, const float* __restrict__ add1,
    const float* __restrict__ add2, float* __restrict__ C,
    bf16_t* __restrict__ Cb,
    int M, int N, int K, int relu, int mode, int swz)
{
    __shared__ __align__(16) bf16_t As[128*64];
    __shared__ __align__(16) bf16_t Bs[128*64];
    const int tid = threadIdx.x;
    int bx = blockIdx.x, by = blockIdx.y;
    if (swz) {
        const int nbx = gridDim.x, nby = gridDim.y;
        const int nwg = nbx * nby;             // divisible by 8
        const int lin = by * nbx + bx;
        const int wg  = (lin & 7) * (nwg >> 3) + (lin >> 3);
        bx = wg / nby;                         // n-major: same-n blocks adjacent
        by = wg % nby;
    }
    const int m0 = by * 128, n0 = bx * 128;
    const int l = tid & 63, w = tid >> 6;
    const int wr = (w >> 1) * 64, wc = (w & 1) * 64;
    const int lr = l & 15, lk = (l >> 4) * 8;

    const int srow = l >> 3, scol = (l & 7) * 8;
    const bf16_t* Ag = A + (size_t)(m0 + w*32 + srow) * K + scol;
    const bf16_t* Wg = W + (size_t)(n0 + w*32 + srow) * K + scol;

    f32x4 z4 = {0.f, 0.f, 0.f, 0.f};
    f32x4 acc[4][4];
    #pragma unroll
    for (int i = 0; i < 4; ++i)
        #pragma unroll
        for (int j = 0; j < 4; ++j) acc[i][j] = z4;

    #pragma unroll
    for (int it = 0; it < 4; ++it) {
        GLD16(Ag + (size_t)(it*8)*K, As + (w*4 + it)*512);
        GLD16(Wg + (size_t)(it*8)*K, Bs + (w*4 + it)*512);
    }

    for (int k0 = 0; k0 < K; k0 += 64) {
        __syncthreads();                       // B1: tile landed
        bf16x8 afr[8], bfr[8];
        #pragma unroll
        for (int kk = 0; kk < 2; ++kk)
            #pragma unroll
            for (int i = 0; i < 4; ++i) {
                afr[kk*4+i] = *(const bf16x8*)&As[(wr + i*16 + lr)*64 + kk*32 + lk];
                bfr[kk*4+i] = *(const bf16x8*)&Bs[(wc + i*16 + lr)*64 + kk*32 + lk];
            }
        __syncthreads();                       // B2: reads done, LDS free
        if (k0 + 64 < K) {
            #pragma unroll
            for (int it = 0; it < 4; ++it) {
                GLD16(Ag + (size_t)(it*8)*K + k0 + 64, As + (w*4 + it)*512);
                GLD16(Wg + (size_t)(it*8)*K + k0 + 64, Bs + (w*4 + it)*512);
            }
        }
        #pragma unroll
        for (int kk = 0; kk < 2; ++kk)
            #pragma unroll
            for (int i = 0; i < 4; ++i)
                #pragma unroll
                for (int j = 0; j < 4; ++j)
                    acc[i][j] = MFMA16(afr[kk*4+i], bfr[kk*4+j], acc[i][j]);
    }

    #pragma unroll
    for (int i = 0; i < 4; ++i) {
        #pragma unroll
        for (int j = 0; j < 4; ++j) {
            const int col  = n0 + wc + j*16 + lr;
            const int row0 = m0 + wr + i*16 + (l >> 4)*4;
            const float bv = bias ? bias[col] : 0.f;
            #pragma unroll
            for (int r2 = 0; r2 < 4; ++r2) {
                const int row = row0 + r2;
                float val = acc[i][j][r2] + bv;
                if (add1) val += add1[(size_t)row*N + col];
                if (add2) val += add2[(size_t)row*N + col];
                if (relu) val = fmaxf(val, 0.f);
                if (mode == 0) C[(size_t)row*N + col] = val;
                else           Cb[(size_t)row*N + col] = (bf16_t)val;
            }
        }
    }
}

// ---------------------------------------------------------------------------
// Fallback logits GEMM (A bf16 via gload_lds, W f32 reg-staged). Unchanged.
// ---------------------------------------------------------------------------
__global__ __launch_bounds__(256) void gemm_bfw32(
    const bf16_t* __restrict__ A, const float* __restrict__ W,
    float* __restrict__ C, int M, int N, int K)
{
    __shared__ __align__(16) bf16_t As[128*64];
    __shared__ __align__(16) bf16_t Bs[128*64];
    const int tid = threadIdx.x;
    const int m0 = blockIdx.y * 128, n0 = blockIdx.x * 128;
    const int l = tid & 63, w = tid >> 6;
    const int wr = (w >> 1) * 64, wc = (w & 1) * 64;
    const int lr = l & 15, lk = (l >> 4) * 8;
    const int srow = l >> 3, scol = (l & 7) * 8;
    const bf16_t* Ag = A + (size_t)(m0 + w*32 + srow) * K + scol;
    const int r = tid >> 1, half = (tid & 1) * 32;
    const float* Wp = W + (size_t)(n0 + r) * K + half;

    f32x4 z4 = {0.f, 0.f, 0.f, 0.f};
    f32x4 acc[4][4];
    #pragma unroll
    for (int i = 0; i < 4; ++i)
        #pragma unroll
        for (int j = 0; j < 4; ++j) acc[i][j] = z4;

    for (int k0 = 0; k0 < K; k0 += 64) {
        float4 wv[8];
        #pragma unroll
        for (int j = 0; j < 8; ++j) wv[j] = *(const float4*)(Wp + k0 + 4*j);
        __syncthreads();
        #pragma unroll
        for (int it = 0; it < 4; ++it)
            GLD16(Ag + (size_t)(it*8)*K + k0, As + (w*4 + it)*512);
        #pragma unroll
        for (int j = 0; j < 4; ++j)
            *(bf16x8*)&Bs[r*64 + half + 8*j] = pack8(wv[2*j], wv[2*j+1]);
        __syncthreads();
        #pragma unroll
        for (int kk = 0; kk < 2; ++kk) {
            bf16x8 afr[4], bfr[4];
            #pragma unroll
            for (int i = 0; i < 4; ++i)
                afr[i] = *(const bf16x8*)&As[(wr + i*16 + lr)*64 + kk*32 + lk];
            #pragma unroll
            for (int j = 0; j < 4; ++j)
                bfr[j] = *(const bf16x8*)&Bs[(wc + j*16 + lr)*64 + kk*32 + lk];
            #pragma unroll
            for (int i = 0; i < 4; ++i)
                #pragma unroll
                for (int j = 0; j < 4; ++j)
                    acc[i][j] = MFMA16(afr[i], bfr[j], acc[i][j]);
        }
    }
    #pragma unroll
    for (int i = 0; i < 4; ++i)
        #pragma unroll
        for (int j = 0; j < 4; ++j) {
            const int col  = n0 + wc + j*16 + lr;
            const int row0 = m0 + wr + i*16 + (l >> 4)*4;
            #pragma unroll
            for (int r2 = 0; r2 < 4; ++r2)
                C[(size_t)(row0 + r2)*N + col] = acc[i][j][r2];
        }
}

// ---------------------------------------------------------------------------
// Fused QKV GEMM (M x 3072): seg 0=q (rope -> qbf), 1=k (rope, scaled_zero
// FOLDED INTO kbf: score*zm == dot(q, k*zm)), 2=v (-> Vt via LDS transpose,
// coalesced stores). Rope pairs = adjacent cols = shfl_xor(val,1).
// ---------------------------------------------------------------------------
__global__ __launch_bounds__(256) void qkv_gemm(
    const bf16_t* __restrict__ A, const bf16_t* __restrict__ Wq,
    const bf16_t* __restrict__ Wk, const bf16_t* __restrict__ Wv,
    const float* __restrict__ qb, const float* __restrict__ vbias,
    const float* __restrict__ ctab, const float* __restrict__ stab,
    const float* __restrict__ fptr,
    bf16_t* __restrict__ qbf, bf16_t* __restrict__ kbf,
    bf16_t* __restrict__ vt, int S)
{
    // smem: As = [0,8192), Bs = [8192,16384) during K-loop;
    // reused as tr[128][134] (c-major) for the seg-2 V transpose.
    __shared__ __align__(16) bf16_t smem[128*134];
    bf16_t* As = smem;
    bf16_t* Bs = smem + 8192;
    const int tid = threadIdx.x;
    const int seg = blockIdx.x >> 3;              // 0=q 1=k 2=v
    const int n0  = (blockIdx.x & 7) * 128;       // col within segment
    const int m0  = blockIdx.y * 128;
    const bf16_t* W = (seg == 0) ? Wq : (seg == 1) ? Wk : Wv;
    const int K = DD;
    const int l = tid & 63, w = tid >> 6;
    const int wr = (w >> 1) * 64, wc = (w & 1) * 64;
    const int lr = l & 15, lk = (l >> 4) * 8;
    const int g4 = l >> 4;

    const int srow = l >> 3, scol = (l & 7) * 8;
    const bf16_t* Ag = A + (size_t)(m0 + w*32 + srow) * K + scol;
    const bf16_t* Wg = W + (size_t)(n0 + w*32 + srow) * K + scol;

    f32x4 z4 = {0.f, 0.f, 0.f, 0.f};
    f32x4 acc[4][4];
    #pragma unroll
    for (int i = 0; i < 4; ++i)
        #pragma unroll
        for (int j = 0; j < 4; ++j) acc[i][j] = z4;

    #pragma unroll
    for (int it = 0; it < 4; ++it) {
        GLD16(Ag + (size_t)(it*8)*K, As + (w*4 + it)*512);
        GLD16(Wg + (size_t)(it*8)*K, Bs + (w*4 + it)*512);
    }

    for (int k0 = 0; k0 < K; k0 += 64) {
        __syncthreads();
        bf16x8 afr[8], bfr[8];
        #pragma unroll
        for (int kk = 0; kk < 2; ++kk)
            #pragma unroll
            for (int i = 0; i < 4; ++i) {
                afr[kk*4+i] = *(const bf16x8*)&As[(wr + i*16 + lr)*64 + kk*32 + lk];
                bfr[kk*4+i] = *(const bf16x8*)&Bs[(wc + i*16 + lr)*64 + kk*32 + lk];
            }
        __syncthreads();
        if (k0 + 64 < K) {
            #pragma unroll
            for (int it = 0; it < 4; ++it) {
                GLD16(Ag + (size_t)(it*8)*K + k0 + 64, As + (w*4 + it)*512);
                GLD16(Wg + (size_t)(it*8)*K + k0 + 64, Bs + (w*4 + it)*512);
            }
        }
        #pragma unroll
        for (int kk = 0; kk < 2; ++kk)
            #pragma unroll
            for (int i = 0; i < 4; ++i)
                #pragma unroll
                for (int j = 0; j < 4; ++j)
                    acc[i][j] = MFMA16(afr[kk*4+i], bfr[kk*4+j], acc[i][j]);
    }

    float zf = 0.f;
    if (seg == 1) {
        float f = fptr[0];
        float sp = (f > 20.f) ? f : log1pf(expf(f));
        zf = fminf(fmaxf(sp, 1e-5f), 0.1f);
    }

    #pragma unroll
    for (int i = 0; i < 4; ++i) {
        float ov[4][4];
        #pragma unroll
        for (int j = 0; j < 4; ++j) {
            const int col = n0 + wc + j*16 + lr;          // 0..1023 within seg
            const float bv = (seg == 0) ? qb[col] : (seg == 2) ? vbias[col] : 0.f;
            const int d  = col & 63;
            const int pi = d >> 1;
            #pragma unroll
            for (int r2 = 0; r2 < 4; ++r2) {
                const int row = m0 + wr + i*16 + g4*4 + r2;
                const int s  = row & (SEQ - 1);
                float val = acc[i][j][r2] + bv;
                if (seg < 2) {
                    // rope pair (even,odd) lives in lanes lr, lr^1
                    float partner = __shfl_xor(val, 1, 64);
                    float c  = ctab[s*32 + pi];
                    float sn = stab[s*32 + pi];
                    val = ((d & 1) == 0) ? (val*c - partner*sn)
                                         : (partner*sn + val*c);
                }
                ov[j][r2] = val;
            }
        }
        if (seg == 1) {
            // scaled_zero: d==0 value of each row is held by lane g4*16 (j=0).
            #pragma unroll
            for (int r2 = 0; r2 < 4; ++r2) {
                float z0 = __shfl(ov[0][r2], (l & 48), 64);
                float zr = (z0 == 0.0f) ? zf : 1.0f;
                #pragma unroll
                for (int j = 0; j < 4; ++j) ov[j][r2] *= zr;
            }
        }
        #pragma unroll
        for (int j = 0; j < 4; ++j) {
            const int col = n0 + wc + j*16 + lr;
            #pragma unroll
            for (int r2 = 0; r2 < 4; ++r2) {
                const int row = m0 + wr + i*16 + g4*4 + r2;
                if (seg == 0)      qbf[(size_t)row*DD + col] = (bf16_t)ov[j][r2];
                else if (seg == 1) kbf[(size_t)row*DD + col] = (bf16_t)ov[j][r2];
                else smem[(col - n0)*134 + (row - m0)] = (bf16_t)ov[j][r2];
            }
        }
    }

    if (seg == 2) {
        __syncthreads();          // tr complete
        const int bb2 = m0 >> 10, s0 = m0 & (SEQ - 1);
        const int d2 = tid >> 1, sh = (tid & 1) * 64;
        const int hh2 = (n0 >> 6) + (d2 >> 6);
        const int dd2 = d2 & 63;
        bf16_t* dst = vt + ((size_t)(bb2*HEADS + hh2)*HDIM + dd2)*S + s0 + sh;
        const bf16_t* srcp = smem + d2*134 + sh;
        #pragma unroll
        for (int k2 = 0; k2 < 8; ++k2)
            *(bf16x8*)(dst + k2*8) = *(const bf16x8*)(srcp + k2*8);
    }
}

// ---------------------------------------------------------------------------
// Fused flash attention (scaled_zero pre-folded into kbf; pure causal mask).
// Per (64-q-row tile, bh) block, 4 waves (16 q each). Swapped QK^T; online
// softmax in regs; causal tail added analytically via vsuf; PV from LDS.
// ---------------------------------------------------------------------------
__global__ __launch_bounds__(256) void attn_fused(
    const bf16_t* __restrict__ qbf, const bf16_t* __restrict__ kbf,
    const bf16_t* __restrict__ Vt,
    const float* __restrict__ vsuf, bf16_t* __restrict__ O, int S)
{
    __shared__ __align__(16) bf16_t Ks[128*64];   // [k][64]
    __shared__ __align__(16) bf16_t Vs[64*128];   // [d][128]
    __shared__ __align__(16) bf16_t Ps[64*128];   // [q][128], XOR-swizzled

    const int tid = threadIdx.x;
    const int qt = (gridDim.x - 1) - blockIdx.x;  // heavy tiles dispatch first
    const int q0 = qt * 64;
    const int bh = blockIdx.y, b = bh >> 4, hh = bh & 15;
    const int l = tid & 63, w = tid >> 6;
    const int lr = l & 15, g = l >> 4;
    const int lk = g * 8;
    const int ktm = q0 >> 7;                 // last causal 128-key tile
    const int cnt = S - 128*(ktm + 1);       // fully-masked tail key count
    const int myq = q0 + w*16 + lr;          // q this lane holds stats for
    const int qloc = w*16 + lr;              // row in Ps

    bf16x8 qfr[2];
    {
        const bf16_t* qp = qbf + (size_t)(b*S + myq)*DD + hh*HDIM;
        qfr[0] = *(const bf16x8*)(qp + lk);
        qfr[1] = *(const bf16x8*)(qp + 32 + lk);
    }

    float m_run = (cnt > 0) ? 0.f : -3.0e38f;   // masked zeros participate
    float psum = 0.f;
    f32x4 z4 = {0.f, 0.f, 0.f, 0.f};
    f32x4 acc[4];                  // O[q = w*16 + g*4+r][d = j*16+lr]
    #pragma unroll
    for (int j = 0; j < 4; ++j) acc[j] = z4;

    const int sr = l >> 3, sc = (l & 7) * 8;

    for (int kt = 0; kt <= ktm; ++kt) {
        __syncthreads();                       // Ks/Vs free from prev iter
        const bf16_t* Kg = kbf + (size_t)(b*S + kt*128)*DD + hh*HDIM;
        #pragma unroll
        for (int it = 0; it < 4; ++it) {
            const int krow = (w*4 + it)*8 + sr;
            GLD16(Kg + (size_t)krow*DD + sc, Ks + (w*4 + it)*512);
        }
        const bf16_t* Vg = Vt + ((size_t)bh*HDIM)*S + kt*128;
        #pragma unroll
        for (int it = 0; it < 4; ++it) {
            const int drow = (w*4 + it)*4 + g;
            GLD16(Vg + (size_t)drow*S + lr*8, Vs + (w*4 + it)*512);
        }
        __syncthreads();                       // tiles staged (vmcnt drained)

        // QK^T: A = K rows -> C rows = k; B = Q rows -> C cols = q
        float sv[8][4];
        float mtile = -3.0e38f;
        #pragma unroll
        for (int f = 0; f < 8; ++f) {
            bf16x8 ka0 = *(const bf16x8*)&Ks[(f*16 + lr)*64 + lk];
            bf16x8 ka1 = *(const bf16x8*)&Ks[(f*16 + lr)*64 + 32 + lk];
            f32x4 t = z4;
            t = MFMA16(ka0, qfr[0], t);
            t = MFMA16(ka1, qfr[1], t);
            #pragma unroll
            for (int r = 0; r < 4; ++r) {
                const int key = kt*128 + f*16 + g*4 + r;
                float v = t[r] * 0.125f;       // HD^-0.5; zm folded into kbf
                v = (key <= myq) ? v : 0.f;
                sv[f][r] = v;
                mtile = fmaxf(mtile, v);
            }
        }
        mtile = fmaxf(mtile, __shfl_xor(mtile, 16, 64));
        mtile = fmaxf(mtile, __shfl_xor(mtile, 32, 64));
        const float m_new = fmaxf(m_run, mtile);
        const float fac = expf(m_run - m_new);
        m_run = m_new;

        float ps_t = 0.f;
        #pragma unroll
        for (int f = 0; f < 8; ++f) {
            bf16x4 pk;
            #pragma unroll
            for (int r = 0; r < 4; ++r) {
                float p = expf(sv[f][r] - m_new);
                ps_t += p;
                pk[r] = (bf16_t)p;
            }
            const int byteoff = (qloc*256 + f*32 + g*8) ^ ((lr & 7) << 4);
            *(bf16x4*)((char*)Ps + byteoff) = pk;
        }
        ps_t += __shfl_xor(ps_t, 16, 64);
        ps_t += __shfl_xor(ps_t, 32, 64);
        psum = psum * fac + ps_t;

        #pragma unroll
        for (int r = 0; r < 4; ++r) {
            const float fr_ = __shfl(fac, g*4 + r, 64);
            #pragma unroll
            for (int j = 0; j < 4; ++j) acc[j][r] *= fr_;
        }

        #pragma unroll
        for (int kk = 0; kk < 4; ++kk) {
            const int rboff = (qloc*256 + kk*64 + g*16) ^ ((lr & 7) << 4);
            bf16x8 pa = *(const bf16x8*)((char*)Ps + rboff);
            #pragma unroll
            for (int j = 0; j < 4; ++j) {
                bf16x8 vb = *(const bf16x8*)&Vs[(j*16 + lr)*128 + kk*32 + lk];
                acc[j] = MFMA16(pa, vb, acc[j]);
            }
        }
    }

    if (cnt > 0) psum += (float)cnt * expf(-m_run);

    #pragma unroll
    for (int r = 0; r < 4; ++r) {
        const float m_r  = __shfl(m_run, g*4 + r, 64);
        const float ps_r = __shfl(psum,  g*4 + r, 64);
        const float inv = 1.0f / ps_r;
        const float tailf = (cnt > 0) ? expf(-m_r) : 0.f;
        const int qrow = q0 + w*16 + g*4 + r;
        const size_t rowbase = (size_t)(b*S + qrow)*DD + hh*HDIM;
        #pragma unroll
        for (int j = 0; j < 4; ++j) {
            float val = acc[j][r];
            if (cnt > 0)
                val += tailf * vsuf[((size_t)bh*8 + ktm + 1)*64 + j*16 + lr];
            O[rowbase + j*16 + lr] = (bf16_t)(val * inv);
        }
    }
}

// ---------------------------------------------------------------------------
extern "C" void kernel_launch(void* const* d_in, const int* in_sizes, int n_in,
                              void* d_out, int out_size, void* d_ws, size_t ws_size,
                              hipStream_t stream)
{
    const int S = SEQ;
    const int B = in_sizes[0] / S;     // 2
    const int M = B * S;               // 2048
    const int BH = B * HEADS;          // 32

    const int*   x       = (const int*)  d_in[0];
    const float* tok_emb = (const float*)d_in[2];
    const float* pos_emb = (const float*)d_in[3];
    const float* rif     = (const float*)d_in[4];
    const float* rbias   = (const float*)d_in[5];
    const float* brif    = (const float*)d_in[6];
    const float* bbias   = (const float*)d_in[7];
    const float* lna     = (const float*)d_in[8];
    const float* qw      = (const float*)d_in[9];
    const float* qb      = (const float*)d_in[10];
    const float* kw      = (const float*)d_in[11];
    const float* vw      = (const float*)d_in[12];
    const float* vbias   = (const float*)d_in[13];
    const float* ow      = (const float*)d_in[14];
    const float* ob      = (const float*)d_in[15];
    const float* factor  = (const float*)d_in[16];
    const float* lnc     = (const float*)d_in[17];
    const float* w1      = (const float*)d_in[18];
    const float* b1      = (const float*)d_in[19];
    const float* w2      = (const float*)d_in[20];
    const float* b2      = (const float*)d_in[21];
    const float* lnd     = (const float*)d_in[22];

    char* ob_ = (char*)d_out;
    const size_t MiB = 1024*1024;
    float*  h      = (float*)(ob_ + 0*MiB);      // 8 MiB
    float*  h2     = (float*)(ob_ + 8*MiB);      // 8 MiB
    bf16_t* qbf    = (bf16_t*)(ob_ + 16*MiB);    // 4 MiB
    bf16_t* kbf    = (bf16_t*)(ob_ + 20*MiB);    // 4 MiB
    bf16_t* vt     = (bf16_t*)(ob_ + 24*MiB);    // 4 MiB  Vt[b][h][d][S]
    bf16_t* attno  = (bf16_t*)(ob_ + 28*MiB);    // 4 MiB
    bf16_t* m1     = (bf16_t*)(ob_ + 32*MiB);    // 16 MiB
    float*  ctab   = (float*)(ob_ + 50*MiB);     // 128 KiB
    float*  stab   = (float*)(ob_ + 51*MiB);     // 128 KiB
    float*  vsuf   = (float*)(ob_ + 52*MiB);     // 64 KiB
    bf16_t* qw_bf  = (bf16_t*)(ob_ + 64*MiB);    // 8 MiB (4 layers)
    bf16_t* kw_bf  = (bf16_t*)(ob_ + 72*MiB);
    bf16_t* vw_bf  = (bf16_t*)(ob_ + 80*MiB);
    bf16_t* ow_bf  = (bf16_t*)(ob_ + 88*MiB);
    bf16_t* w1_bf  = (bf16_t*)(ob_ + 96*MiB);    // 32 MiB
    bf16_t* w2_bf  = (bf16_t*)(ob_ + 128*MiB);   // 32 MiB -> ends 160 < 250 MiB

    bf16_t* hn      = (bf16_t*)d_ws;             // 4 MiB
    bf16_t* temb_bf = (bf16_t*)((char*)d_ws + 4*MiB);
    const bool big_ws = ws_size >= (size_t)(70*MiB);

    const long NW_D = (long)NLAYER * DD * DD;
    const long NW_F = (long)NLAYER * FFDIM * DD;
    const long NW_E = (long)NVOCAB * DD;
    cvt_kernel<<<NW_D/2048, 256, 0, stream>>>(qw, qw_bf, NW_D);
    cvt_kernel<<<NW_D/2048, 256, 0, stream>>>(kw, kw_bf, NW_D);
    cvt_kernel<<<NW_D/2048, 256, 0, stream>>>(vw, vw_bf, NW_D);
    cvt_kernel<<<NW_D/2048, 256, 0, stream>>>(ow, ow_bf, NW_D);
    cvt_kernel<<<NW_F/2048, 256, 0, stream>>>(w1, w1_bf, NW_F);
    cvt_kernel<<<NW_F/2048, 256, 0, stream>>>(w2, w2_bf, NW_F);
    if (big_ws)
        cvt_kernel<<<(NW_E+2047)/2048, 256, 0, stream>>>(tok_emb, temb_bf, NW_E);
    ropetab_kernel<<<(S*32)/256, 256, 0, stream>>>(brif, bbias, ctab, stab);

    dim3 gD(DD/128,     M/128);
    dim3 gF(FFDIM/128,  M/128);
    dim3 gV(NVOCAB/128, M/128);
    dim3 gQKV(3*DD/128, M/128);
    dim3 gATT(S/64, BH);

    embed_rope_kernel<<<M, 512, 0, stream>>>(x, tok_emb, pos_emb, rif, rbias, h, S);

    for (int l = 0; l < NLAYER; ++l) {
        const size_t wo = (size_t)l * DD * DD;
        const size_t fo = (size_t)l * FFDIM * DD;
        rmsnorm_kernel<<<M, 256, 0, stream>>>(h, lna + l*DD, hn);
        qkv_gemm<<<gQKV, 256, 0, stream>>>(hn, qw_bf + wo, kw_bf + wo, vw_bf + wo,
                                           qb + l*DD, vbias + l*DD, ctab, stab,
                                           factor + l, qbf, kbf, vt, S);
        vsuf_kernel<<<BH, 256, 0, stream>>>(vt, vsuf, S);
        attn_fused<<<gATT, 256, 0, stream>>>(qbf, kbf, vt, vsuf, attno, S);
        // h2 = attno @ ow^T + ob + h
        gemm_bf<<<gD, 256, 0, stream>>>(attno, ow_bf + wo, ob + l*DD, h, nullptr,
                                        h2, nullptr, M, DD, DD, 0, 0, 0);
        rmsnorm_kernel<<<M, 256, 0, stream>>>(h2, lnc + l*DD, hn);
        gemm_bf<<<gF, 256, 0, stream>>>(hn, w1_bf + fo, b1 + l*FFDIM, nullptr, nullptr,
                                        nullptr, m1, M, FFDIM, DD, 1, 1, 0);
        // h_new = m1 @ w2^T + b2 + h2 + h   (== 2*h_old + attn + mlp)
        gemm_bf<<<gD, 256, 0, stream>>>(m1, w2_bf + fo, b2 + l*DD, h2, h,
                                        h, nullptr, M, DD, FFDIM, 0, 0, 0);
    }

    rmsnorm_kernel<<<M, 256, 0, stream>>>(h, lnd, hn);
    if (big_ws)
        gemm_bf<<<gV, 256, 0, stream>>>(hn, temb_bf, nullptr, nullptr, nullptr,
                                        (float*)d_out, nullptr, M, NVOCAB, DD, 0, 0, 1);
    else
        gemm_bfw32<<<gV, 256, 0, stream>>>(hn, tok_emb, (float*)d_out, M, NVOCAB, DD);
}

// Round 9
// 1260.922 us; speedup vs baseline: 1.2630x; 1.1626x over previous
//
#include <hip/hip_runtime.h>
#include <hip/hip_bf16.h>

#define DD 1024
#define HEADS 16
#define HDIM 64
#define NLAYER 4
#define FFDIM 4096
#define NVOCAB 32000
#define SEQ 1024

typedef __bf16 bf16_t;
typedef __bf16 bf16x8 __attribute__((ext_vector_type(8)));
typedef __bf16 bf16x4 __attribute__((ext_vector_type(4)));
typedef float f32x4 __attribute__((ext_vector_type(4)));

#define MFMA16(a, b, c) __builtin_amdgcn_mfma_f32_16x16x32_bf16((a), (b), (c), 0, 0, 0)

// async global->LDS, 16B per lane, dest = wave-uniform base + lane*16
#define GLD16(gp, lp) \
    __builtin_amdgcn_global_load_lds( \
        (const __attribute__((address_space(1))) void*)(gp), \
        (__attribute__((address_space(3))) void*)(lp), 16, 0, 0)

// raw barrier (no implicit vmcnt/lgkm drain) with compile-time motion fences
#define BAR() do { __builtin_amdgcn_sched_barrier(0); \
                   __builtin_amdgcn_s_barrier(); \
                   __builtin_amdgcn_sched_barrier(0); } while (0)
#define WAITVM(n) asm volatile("s_waitcnt vmcnt(" #n ")" ::: "memory")

static __device__ __forceinline__ bf16x8 pack8(float4 u, float4 v) {
    bf16x8 r;
    r[0] = (bf16_t)u.x; r[1] = (bf16_t)u.y; r[2] = (bf16_t)u.z; r[3] = (bf16_t)u.w;
    r[4] = (bf16_t)v.x; r[5] = (bf16_t)v.y; r[6] = (bf16_t)v.z; r[7] = (bf16_t)v.w;
    return r;
}

// ---------------------------------------------------------------------------
// f32 -> bf16 bulk convert (weights, once per launch). n % 2048 == 0.
// ---------------------------------------------------------------------------
__global__ __launch_bounds__(256) void cvt_kernel(
    const float* __restrict__ src, bf16_t* __restrict__ dst, long n)
{
    long i = ((long)blockIdx.x * 256 + threadIdx.x) * 8;
    if (i < n) {
        float4 a = *(const float4*)(src + i);
        float4 b = *(const float4*)(src + i + 4);
        *(bf16x8*)(dst + i) = pack8(a, b);
    }
}

// ---------------------------------------------------------------------------
// Head-rope cos/sin tables: [S][32]
// ---------------------------------------------------------------------------
__global__ __launch_bounds__(256) void ropetab_kernel(
    const float* __restrict__ inv_freq, const float* __restrict__ rbias,
    float* __restrict__ ctab, float* __restrict__ stab)
{
    int idx = blockIdx.x * 256 + threadIdx.x;     // s*32 + i
    int s = idx >> 5, i = idx & 31;
    float fr = (float)s * inv_freq[i] + rbias[idx];
    ctab[idx] = cosf(fr);
    stab[idx] = sinf(fr);
}

// ---------------------------------------------------------------------------
// Embedding + decoder-level rotary
// ---------------------------------------------------------------------------
__global__ __launch_bounds__(512) void embed_rope_kernel(
    const int* __restrict__ x, const float* __restrict__ tok_emb,
    const float* __restrict__ pos_emb, const float* __restrict__ inv_freq,
    const float* __restrict__ rbias, float* __restrict__ h, int S)
{
    const int row = blockIdx.x;      // b*S + s
    const int s = row % S;
    const int i = threadIdx.x;       // 0..511 pair index
    const int tok = x[row];
    const float* e = tok_emb + (size_t)tok * DD;
    const float* p = pos_emb + (size_t)s * DD;
    float a = e[2*i]   + p[2*i];
    float b = e[2*i+1] + p[2*i+1];
    float fr = (float)s * inv_freq[i] + rbias[(size_t)s * (DD/2) + i];
    float c = cosf(fr), sn = sinf(fr);
    h[(size_t)row*DD + 2*i]   = a*c - b*sn;
    h[(size_t)row*DD + 2*i+1] = a*sn + b*c;
}

// ---------------------------------------------------------------------------
// RMSNorm with bf16 output
// ---------------------------------------------------------------------------
__global__ __launch_bounds__(256) void rmsnorm_kernel(
    const float* __restrict__ x, const float* __restrict__ w,
    bf16_t* __restrict__ y)
{
    const int row = blockIdx.x;
    const float* xr = x + (size_t)row * DD;
    float ss = 0.f;
    for (int j = threadIdx.x; j < DD; j += 256) { float v = xr[j]; ss += v*v; }
    for (int off = 32; off > 0; off >>= 1) ss += __shfl_down(ss, off, 64);
    __shared__ float r[4];
    if ((threadIdx.x & 63) == 0) r[threadIdx.x >> 6] = ss;
    __syncthreads();
    float tot = r[0] + r[1] + r[2] + r[3];
    float sc = rsqrtf(tot * (1.0f/(float)DD) + 1e-8f);
    for (int j = threadIdx.x; j < DD; j += 256)
        y[(size_t)row*DD + j] = (bf16_t)(xr[j] * sc * w[j]);
}

// ---------------------------------------------------------------------------
// V tile-suffix sums: vsuf[bh][t][d] = sum_{k >= 128t} Vt[bh][d][k], t=1..7
// ---------------------------------------------------------------------------
__global__ __launch_bounds__(256) void vsuf_kernel(
    const bf16_t* __restrict__ Vt, float* __restrict__ vsuf, int S)
{
    __shared__ float part[4][7][64];
    const int d = threadIdx.x & 63, s4 = threadIdx.x >> 6;
    const int bh = blockIdx.x;
    const bf16_t* vp = Vt + ((size_t)bh*HDIM + d)*S;
    for (int t = 1; t <= 7; ++t) {
        float a = 0.f;
        const bf16_t* p = vp + t*128 + s4*32;
        #pragma unroll
        for (int c = 0; c < 4; ++c) {
            bf16x8 v = *(const bf16x8*)(p + c*8);
            #pragma unroll
            for (int e = 0; e < 8; ++e) a += (float)v[e];
        }
        part[s4][t-1][d] = a;
    }
    __syncthreads();
    if (s4 == 0) {
        float acc2 = 0.f;
        for (int t = 7; t >= 1; --t) {
            acc2 += part[0][t-1][d] + part[1][t-1][d] + part[2][t-1][d] + part[3][t-1][d];
            vsuf[((size_t)bh*8 + t)*64 + d] = acc2;
        }
    }
}

// ---------------------------------------------------------------------------
// bf16 MFMA GEMM 128x128, reg-prefetch schedule (unchanged, proven).
// ---------------------------------------------------------------------------
__global__ __launch_bounds__(256) void gemm_bf(
    const bf16_t* __restrict__ A, const bf16_t* __restrict__ W,
    const float* __restrict__ bias, const float* __restrict__ add1,
    const float* __restrict__ add2, float* __restrict__ C,
    bf16_t* __restrict__ Cb,
    int M, int N, int K, int relu, int mode, int swz)
{
    __shared__ __align__(16) bf16_t As[128*64];
    __shared__ __align__(16) bf16_t Bs[128*64];
    const int tid = threadIdx.x;
    int bx = blockIdx.x, by = blockIdx.y;
    if (swz) {
        const int nbx = gridDim.x, nby = gridDim.y;
        const int nwg = nbx * nby;             // divisible by 8
        const int lin = by * nbx + bx;
        const int wg  = (lin & 7) * (nwg >> 3) + (lin >> 3);
        bx = wg / nby;                         // n-major: same-n blocks adjacent
        by = wg % nby;
    }
    const int m0 = by * 128, n0 = bx * 128;
    const int l = tid & 63, w = tid >> 6;
    const int wr = (w >> 1) * 64, wc = (w & 1) * 64;
    const int lr = l & 15, lk = (l >> 4) * 8;

    const int srow = l >> 3, scol = (l & 7) * 8;
    const bf16_t* Ag = A + (size_t)(m0 + w*32 + srow) * K + scol;
    const bf16_t* Wg = W + (size_t)(n0 + w*32 + srow) * K + scol;

    f32x4 z4 = {0.f, 0.f, 0.f, 0.f};
    f32x4 acc[4][4];
    #pragma unroll
    for (int i = 0; i < 4; ++i)
        #pragma unroll
        for (int j = 0; j < 4; ++j) acc[i][j] = z4;

    #pragma unroll
    for (int it = 0; it < 4; ++it) {
        GLD16(Ag + (size_t)(it*8)*K, As + (w*4 + it)*512);
        GLD16(Wg + (size_t)(it*8)*K, Bs + (w*4 + it)*512);
    }

    for (int k0 = 0; k0 < K; k0 += 64) {
        __syncthreads();                       // B1: tile landed
        bf16x8 afr[8], bfr[8];
        #pragma unroll
        for (int kk = 0; kk < 2; ++kk)
            #pragma unroll
            for (int i = 0; i < 4; ++i) {
                afr[kk*4+i] = *(const bf16x8*)&As[(wr + i*16 + lr)*64 + kk*32 + lk];
                bfr[kk*4+i] = *(const bf16x8*)&Bs[(wc + i*16 + lr)*64 + kk*32 + lk];
            }
        __syncthreads();                       // B2: reads done, LDS free
        if (k0 + 64 < K) {
            #pragma unroll
            for (int it = 0; it < 4; ++it) {
                GLD16(Ag + (size_t)(it*8)*K + k0 + 64, As + (w*4 + it)*512);
                GLD16(Wg + (size_t)(it*8)*K + k0 + 64, Bs + (w*4 + it)*512);
            }
        }
        #pragma unroll
        for (int kk = 0; kk < 2; ++kk)
            #pragma unroll
            for (int i = 0; i < 4; ++i)
                #pragma unroll
                for (int j = 0; j < 4; ++j)
                    acc[i][j] = MFMA16(afr[kk*4+i], bfr[kk*4+j], acc[i][j]);
    }

    #pragma unroll
    for (int i = 0; i < 4; ++i) {
        #pragma unroll
        for (int j = 0; j < 4; ++j) {
            const int col  = n0 + wc + j*16 + lr;
            const int row0 = m0 + wr + i*16 + (l >> 4)*4;
            const float bv = bias ? bias[col] : 0.f;
            #pragma unroll
            for (int r2 = 0; r2 < 4; ++r2) {
                const int row = row0 + r2;
                float val = acc[i][j][r2] + bv;
                if (add1) val += add1[(size_t)row*N + col];
                if (add2) val += add2[(size_t)row*N + col];
                if (relu) val = fmaxf(val, 0.f);
                if (mode == 0) C[(size_t)row*N + col] = val;
                else           Cb[(size_t)row*N + col] = (bf16_t)val;
            }
        }
    }
}

// ---------------------------------------------------------------------------
// Small-tile GEMM 64x128 (grid-doubling for N=1024 shapes: o-proj, mlp2).
// Same reg-prefetch schedule. 4 waves: 2M x 2N, per-wave 32x64 (2x4 frags).
// ---------------------------------------------------------------------------
__global__ __launch_bounds__(256) void gemm_bf_s(
    const bf16_t* __restrict__ A, const bf16_t* __restrict__ W,
    const float* __restrict__ bias, const float* __restrict__ add1,
    const float* __restrict__ add2, float* __restrict__ C,
    int M, int N, int K)
{
    __shared__ __align__(16) bf16_t As[64*64];
    __shared__ __align__(16) bf16_t Bs[128*64];
    const int tid = threadIdx.x;
    const int m0 = blockIdx.y * 64, n0 = blockIdx.x * 128;
    const int l = tid & 63, w = tid >> 6;
    const int wr = (w >> 1) * 32, wc = (w & 1) * 64;
    const int lr = l & 15, lk = (l >> 4) * 8;

    const int srow = l >> 3, scol = (l & 7) * 8;
    const bf16_t* Ag = A + (size_t)(m0 + w*16 + srow) * K + scol;   // 2 slots/wave
    const bf16_t* Wg = W + (size_t)(n0 + w*32 + srow) * K + scol;   // 4 slots/wave

    f32x4 z4 = {0.f, 0.f, 0.f, 0.f};
    f32x4 acc[2][4];
    #pragma unroll
    for (int i = 0; i < 2; ++i)
        #pragma unroll
        for (int j = 0; j < 4; ++j) acc[i][j] = z4;

    #pragma unroll
    for (int it = 0; it < 2; ++it)
        GLD16(Ag + (size_t)(it*8)*K, As + (w*2 + it)*512);
    #pragma unroll
    for (int it = 0; it < 4; ++it)
        GLD16(Wg + (size_t)(it*8)*K, Bs + (w*4 + it)*512);

    for (int k0 = 0; k0 < K; k0 += 64) {
        __syncthreads();                       // B1: tile landed
        bf16x8 afr[4], bfr[8];
        #pragma unroll
        for (int kk = 0; kk < 2; ++kk) {
            #pragma unroll
            for (int i = 0; i < 2; ++i)
                afr[kk*2+i] = *(const bf16x8*)&As[(wr + i*16 + lr)*64 + kk*32 + lk];
            #pragma unroll
            for (int j = 0; j < 4; ++j)
                bfr[kk*4+j] = *(const bf16x8*)&Bs[(wc + j*16 + lr)*64 + kk*32 + lk];
        }
        __syncthreads();                       // B2: reads done, LDS free
        if (k0 + 64 < K) {
            #pragma unroll
            for (int it = 0; it < 2; ++it)
                GLD16(Ag + (size_t)(it*8)*K + k0 + 64, As + (w*2 + it)*512);
            #pragma unroll
            for (int it = 0; it < 4; ++it)
                GLD16(Wg + (size_t)(it*8)*K + k0 + 64, Bs + (w*4 + it)*512);
        }
        #pragma unroll
        for (int kk = 0; kk < 2; ++kk)
            #pragma unroll
            for (int i = 0; i < 2; ++i)
                #pragma unroll
                for (int j = 0; j < 4; ++j)
                    acc[i][j] = MFMA16(afr[kk*2+i], bfr[kk*4+j], acc[i][j]);
    }

    #pragma unroll
    for (int i = 0; i < 2; ++i) {
        #pragma unroll
        for (int j = 0; j < 4; ++j) {
            const int col  = n0 + wc + j*16 + lr;
            const int row0 = m0 + wr + i*16 + (l >> 4)*4;
            const float bv = bias ? bias[col] : 0.f;
            #pragma unroll
            for (int r2 = 0; r2 < 4; ++r2) {
                const int row = row0 + r2;
                float val = acc[i][j][r2] + bv;
                if (add1) val += add1[(size_t)row*N + col];
                if (add2) val += add2[(size_t)row*N + col];
                C[(size_t)row*N + col] = val;
            }
        }
    }
}

// ---------------------------------------------------------------------------
// 256x256 8-phase GEMM (T2 swizzle + T3/T4 counted vmcnt + T5 setprio).
// K fixed = 1024 (logits). 512 thr / 8 waves (2M x 4N), per-wave 128x64.
// LDS 128 KiB dynamic: [buf][A|B][256][64] bf16, double-buffered.
// Stage slots/iter (e=2i,o=2i+1,e'=2i+2,o'=2i+3): ph1,2:o.A0/A1; ph3,4:e'.B0/B1;
// ph5,6:e'.A0/A1; ph7,8:o'.B0/B1. vmcnt(4) at ph4/ph8 (vmcnt(0) tail).
// st_16x32: read col ^= (row&4)<<3 bytes; stage source pre-permuted (rule 21).
// ---------------------------------------------------------------------------
__global__ __launch_bounds__(512, 2) void gemm256_bf(
    const bf16_t* __restrict__ A, const bf16_t* __restrict__ W,
    float* __restrict__ C, int M, int N)
{
    extern __shared__ __align__(16) char dynsm[];
    bf16_t* TILE = (bf16_t*)dynsm;
    const int tid = threadIdx.x;
    // n-major XCD-chunked swizzle (nwg = 125*8 = 1000, %8 == 0)
    const int nbx = gridDim.x, nby = gridDim.y;
    const int nwg = nbx * nby;
    const int lin = blockIdx.y * nbx + blockIdx.x;
    const int wg  = (lin & 7) * (nwg >> 3) + (lin >> 3);
    const int n0 = (wg / nby) * 256, m0 = (wg % nby) * 256;

    const int l = tid & 63, w = tid >> 6;
    const int wm = w >> 2, wn = w & 3;
    const int lr = l & 15, lg = l >> 4;
    const int flp = (l & 4) ? 16 : 0;            // read-side swizzle (elems)
    const int srow = tid >> 3;                   // 0..63 staging row within s-half
    const int scolE = ((tid & 7) * 8) ^ ((tid & 32) ? 16 : 0);  // pre-swizzled src col

    const bf16_t* Ap = A + (size_t)m0 * 1024;
    const bf16_t* Wp = W + (size_t)n0 * 1024;

    auto STG = [&](int buf, int isB, int half, int k0) {
        const bf16_t* G = isB ? Wp : Ap;
        bf16_t* L = TILE + (buf*2 + isB)*16384 + half*8192 + w*512;
        const int rbase = half*128 + srow;
        GLD16(G + (size_t)rbase*1024 + k0 + scolE,          L);
        GLD16(G + (size_t)(rbase + 64)*1024 + k0 + scolE,   L + 4096);
    };
    auto RD_A = [&](int buf, int fi, int kk) -> bf16x8 {
        const int row = wm*128 + fi*16 + lr;
        return *(const bf16x8*)&TILE[(buf*2)*16384 + row*64 + ((kk*32 + lg*8) ^ flp)];
    };
    auto RD_B = [&](int buf, int fj, int kk) -> bf16x8 {
        const int row = wn*64 + fj*16 + lr;
        return *(const bf16x8*)&TILE[(buf*2 + 1)*16384 + row*64 + ((kk*32 + lg*8) ^ flp)];
    };

    f32x4 z4 = {0.f, 0.f, 0.f, 0.f};
    f32x4 acc[8][4];
    #pragma unroll
    for (int i = 0; i < 8; ++i)
        #pragma unroll
        for (int j = 0; j < 4; ++j) acc[i][j] = z4;
    bf16x8 bfr[4][2];

#define DO_PHASE(BUF, P, STAGE_STMT, TAIL_STMT) do {                          \
    bf16x8 a0_0 = RD_A(BUF, 2*(P), 0),   a0_1 = RD_A(BUF, 2*(P), 1);          \
    bf16x8 a1_0 = RD_A(BUF, 2*(P)+1, 0), a1_1 = RD_A(BUF, 2*(P)+1, 1);        \
    if ((P) == 0) {                                                           \
        _Pragma("unroll")                                                     \
        for (int fj = 0; fj < 4; ++fj) {                                      \
            bfr[fj][0] = RD_B(BUF, fj, 0);                                    \
            bfr[fj][1] = RD_B(BUF, fj, 1);                                    \
        }                                                                     \
    }                                                                         \
    STAGE_STMT;                                                               \
    BAR();                                                                    \
    __builtin_amdgcn_s_setprio(1);                                            \
    _Pragma("unroll")                                                         \
    for (int fj = 0; fj < 4; ++fj) {                                          \
        acc[2*(P)][fj]   = MFMA16(a0_0, bfr[fj][0], acc[2*(P)][fj]);          \
        acc[2*(P)][fj]   = MFMA16(a0_1, bfr[fj][1], acc[2*(P)][fj]);          \
        acc[2*(P)+1][fj] = MFMA16(a1_0, bfr[fj][0], acc[2*(P)+1][fj]);        \
        acc[2*(P)+1][fj] = MFMA16(a1_1, bfr[fj][1], acc[2*(P)+1][fj]);        \
    }                                                                         \
    __builtin_amdgcn_s_setprio(0);                                            \
    TAIL_STMT;                                                                \
    BAR();                                                                    \
} while (0)

    // prologue: t0 full + t1.B; force t0 landed (t1.B in flight)
    STG(0, 0, 0, 0);  STG(0, 0, 1, 0);
    STG(0, 1, 0, 0);  STG(0, 1, 1, 0);
    STG(1, 1, 0, 64); STG(1, 1, 1, 64);
    WAITVM(4);
    BAR();

    #pragma unroll 1
    for (int itr = 0; itr < 8; ++itr) {
        const int k_o  = (2*itr + 1) * 64;
        const int k_e2 = (2*itr + 2) * 64;
        const int k_o2 = (2*itr + 3) * 64;
        const bool more = (itr < 7);
        // tile even (buf0), phases 1-4
        DO_PHASE(0, 0, STG(1, 0, 0, k_o), ;);
        DO_PHASE(0, 1, STG(1, 0, 1, k_o), ;);
        DO_PHASE(0, 2, if (more) STG(0, 1, 0, k_e2), ;);
        DO_PHASE(0, 3, if (more) STG(0, 1, 1, k_e2),
                 if (more) { WAITVM(4); } else { WAITVM(0); });
        // tile odd (buf1), phases 5-8
        DO_PHASE(1, 0, if (more) STG(0, 0, 0, k_e2), ;);
        DO_PHASE(1, 1, if (more) STG(0, 0, 1, k_e2), ;);
        DO_PHASE(1, 2, if (more) STG(1, 1, 0, k_o2), ;);
        DO_PHASE(1, 3, if (more) STG(1, 1, 1, k_o2),
                 if (more) { WAITVM(4); });
    }
#undef DO_PHASE

    #pragma unroll
    for (int i = 0; i < 8; ++i) {
        #pragma unroll
        for (int j = 0; j < 4; ++j) {
            const int col  = n0 + wn*64 + j*16 + lr;
            const int row0 = m0 + wm*128 + i*16 + lg*4;
            #pragma unroll
            for (int r2 = 0; r2 < 4; ++r2)
                C[(size_t)(row0 + r2)*N + col] = acc[i][j][r2];
        }
    }
}

// ---------------------------------------------------------------------------
// Fallback logits GEMM (A bf16 via gload_lds, W f32 reg-staged). Unchanged.
// ---------------------------------------------------------------------------
__global__ __launch_bounds__(256) void gemm_bfw32(
    const bf16_t* __restrict__ A, const float* __restrict__ W,
    float* __restrict__ C, int M, int N, int K)
{
    __shared__ __align__(16) bf16_t As[128*64];
    __shared__ __align__(16) bf16_t Bs[128*64];
    const int tid = threadIdx.x;
    const int m0 = blockIdx.y * 128, n0 = blockIdx.x * 128;
    const int l = tid & 63, w = tid >> 6;
    const int wr = (w >> 1) * 64, wc = (w & 1) * 64;
    const int lr = l & 15, lk = (l >> 4) * 8;
    const int srow = l >> 3, scol = (l & 7) * 8;
    const bf16_t* Ag = A + (size_t)(m0 + w*32 + srow) * K + scol;
    const int r = tid >> 1, half = (tid & 1) * 32;
    const float* Wp = W + (size_t)(n0 + r) * K + half;

    f32x4 z4 = {0.f, 0.f, 0.f, 0.f};
    f32x4 acc[4][4];
    #pragma unroll
    for (int i = 0; i < 4; ++i)
        #pragma unroll
        for (int j = 0; j < 4; ++j) acc[i][j] = z4;

    for (int k0 = 0; k0 < K; k0 += 64) {
        float4 wv[8];
        #pragma unroll
        for (int j = 0; j < 8; ++j) wv[j] = *(const float4*)(Wp + k0 + 4*j);
        __syncthreads();
        #pragma unroll
        for (int it = 0; it < 4; ++it)
            GLD16(Ag + (size_t)(it*8)*K + k0, As + (w*4 + it)*512);
        #pragma unroll
        for (int j = 0; j < 4; ++j)
            *(bf16x8*)&Bs[r*64 + half + 8*j] = pack8(wv[2*j], wv[2*j+1]);
        __syncthreads();
        #pragma unroll
        for (int kk = 0; kk < 2; ++kk) {
            bf16x8 afr[4], bfr[4];
            #pragma unroll
            for (int i = 0; i < 4; ++i)
                afr[i] = *(const bf16x8*)&As[(wr + i*16 + lr)*64 + kk*32 + lk];
            #pragma unroll
            for (int j = 0; j < 4; ++j)
                bfr[j] = *(const bf16x8*)&Bs[(wc + j*16 + lr)*64 + kk*32 + lk];
            #pragma unroll
            for (int i = 0; i < 4; ++i)
                #pragma unroll
                for (int j = 0; j < 4; ++j)
                    acc[i][j] = MFMA16(afr[i], bfr[j], acc[i][j]);
        }
    }
    #pragma unroll
    for (int i = 0; i < 4; ++i)
        #pragma unroll
        for (int j = 0; j < 4; ++j) {
            const int col  = n0 + wc + j*16 + lr;
            const int row0 = m0 + wr + i*16 + (l >> 4)*4;
            #pragma unroll
            for (int r2 = 0; r2 < 4; ++r2)
                C[(size_t)(row0 + r2)*N + col] = acc[i][j][r2];
        }
}

// ---------------------------------------------------------------------------
// Fused QKV GEMM (unchanged from round 8: scaled_zero folded into kbf,
// coalesced Vt store via LDS transpose).
// ---------------------------------------------------------------------------
__global__ __launch_bounds__(256) void qkv_gemm(
    const bf16_t* __restrict__ A, const bf16_t* __restrict__ Wq,
    const bf16_t* __restrict__ Wk, const bf16_t* __restrict__ Wv,
    const float* __restrict__ qb, const float* __restrict__ vbias,
    const float* __restrict__ ctab, const float* __restrict__ stab,
    const float* __restrict__ fptr,
    bf16_t* __restrict__ qbf, bf16_t* __restrict__ kbf,
    bf16_t* __restrict__ vt, int S)
{
    __shared__ __align__(16) bf16_t smem[128*134];
    bf16_t* As = smem;
    bf16_t* Bs = smem + 8192;
    const int tid = threadIdx.x;
    const int seg = blockIdx.x >> 3;              // 0=q 1=k 2=v
    const int n0  = (blockIdx.x & 7) * 128;       // col within segment
    const int m0  = blockIdx.y * 128;
    const bf16_t* W = (seg == 0) ? Wq : (seg == 1) ? Wk : Wv;
    const int K = DD;
    const int l = tid & 63, w = tid >> 6;
    const int wr = (w >> 1) * 64, wc = (w & 1) * 64;
    const int lr = l & 15, lk = (l >> 4) * 8;
    const int g4 = l >> 4;

    const int srow = l >> 3, scol = (l & 7) * 8;
    const bf16_t* Ag = A + (size_t)(m0 + w*32 + srow) * K + scol;
    const bf16_t* Wg = W + (size_t)(n0 + w*32 + srow) * K + scol;

    f32x4 z4 = {0.f, 0.f, 0.f, 0.f};
    f32x4 acc[4][4];
    #pragma unroll
    for (int i = 0; i < 4; ++i)
        #pragma unroll
        for (int j = 0; j < 4; ++j) acc[i][j] = z4;

    #pragma unroll
    for (int it = 0; it < 4; ++it) {
        GLD16(Ag + (size_t)(it*8)*K, As + (w*4 + it)*512);
        GLD16(Wg + (size_t)(it*8)*K, Bs + (w*4 + it)*512);
    }

    for (int k0 = 0; k0 < K; k0 += 64) {
        __syncthreads();
        bf16x8 afr[8], bfr[8];
        #pragma unroll
        for (int kk = 0; kk < 2; ++kk)
            #pragma unroll
            for (int i = 0; i < 4; ++i) {
                afr[kk*4+i] = *(const bf16x8*)&As[(wr + i*16 + lr)*64 + kk*32 + lk];
                bfr[kk*4+i] = *(const bf16x8*)&Bs[(wc + i*16 + lr)*64 + kk*32 + lk];
            }
        __syncthreads();
        if (k0 + 64 < K) {
            #pragma unroll
            for (int it = 0; it < 4; ++it) {
                GLD16(Ag + (size_t)(it*8)*K + k0 + 64, As + (w*4 + it)*512);
                GLD16(Wg + (size_t)(it*8)*K + k0 + 64, Bs + (w*4 + it)*512);
            }
        }
        #pragma unroll
        for (int kk = 0; kk < 2; ++kk)
            #pragma unroll
            for (int i = 0; i < 4; ++i)
                #pragma unroll
                for (int j = 0; j < 4; ++j)
                    acc[i][j] = MFMA16(afr[kk*4+i], bfr[kk*4+j], acc[i][j]);
    }

    float zf = 0.f;
    if (seg == 1) {
        float f = fptr[0];
        float sp = (f > 20.f) ? f : log1pf(expf(f));
        zf = fminf(fmaxf(sp, 1e-5f), 0.1f);
    }

    #pragma unroll
    for (int i = 0; i < 4; ++i) {
        float ov[4][4];
        #pragma unroll
        for (int j = 0; j < 4; ++j) {
            const int col = n0 + wc + j*16 + lr;          // 0..1023 within seg
            const float bv = (seg == 0) ? qb[col] : (seg == 2) ? vbias[col] : 0.f;
            const int d  = col & 63;
            const int pi = d >> 1;
            #pragma unroll
            for (int r2 = 0; r2 < 4; ++r2) {
                const int row = m0 + wr + i*16 + g4*4 + r2;
                const int s  = row & (SEQ - 1);
                float val = acc[i][j][r2] + bv;
                if (seg < 2) {
                    float partner = __shfl_xor(val, 1, 64);
                    float c  = ctab[s*32 + pi];
                    float sn = stab[s*32 + pi];
                    val = ((d & 1) == 0) ? (val*c - partner*sn)
                                         : (partner*sn + val*c);
                }
                ov[j][r2] = val;
            }
        }
        if (seg == 1) {
            #pragma unroll
            for (int r2 = 0; r2 < 4; ++r2) {
                float z0 = __shfl(ov[0][r2], (l & 48), 64);
                float zr = (z0 == 0.0f) ? zf : 1.0f;
                #pragma unroll
                for (int j = 0; j < 4; ++j) ov[j][r2] *= zr;
            }
        }
        #pragma unroll
        for (int j = 0; j < 4; ++j) {
            const int col = n0 + wc + j*16 + lr;
            #pragma unroll
            for (int r2 = 0; r2 < 4; ++r2) {
                const int row = m0 + wr + i*16 + g4*4 + r2;
                if (seg == 0)      qbf[(size_t)row*DD + col] = (bf16_t)ov[j][r2];
                else if (seg == 1) kbf[(size_t)row*DD + col] = (bf16_t)ov[j][r2];
                else smem[(col - n0)*134 + (row - m0)] = (bf16_t)ov[j][r2];
            }
        }
    }

    if (seg == 2) {
        __syncthreads();          // tr complete
        const int bb2 = m0 >> 10, s0 = m0 & (SEQ - 1);
        const int d2 = tid >> 1, sh = (tid & 1) * 64;
        const int hh2 = (n0 >> 6) + (d2 >> 6);
        const int dd2 = d2 & 63;
        bf16_t* dst = vt + ((size_t)(bb2*HEADS + hh2)*HDIM + dd2)*S + s0 + sh;
        const bf16_t* srcp = smem + d2*134 + sh;
        #pragma unroll
        for (int k2 = 0; k2 < 8; ++k2)
            *(bf16x8*)(dst + k2*8) = *(const bf16x8*)(srcp + k2*8);
    }
}

// ---------------------------------------------------------------------------
// Fused flash attention (unchanged from round 8).
// ---------------------------------------------------------------------------
__global__ __launch_bounds__(256) void attn_fused(
    const bf16_t* __restrict__ qbf, const bf16_t* __restrict__ kbf,
    const bf16_t* __restrict__ Vt,
    const float* __restrict__ vsuf, bf16_t* __restrict__ O, int S)
{
    __shared__ __align__(16) bf16_t Ks[128*64];   // [k][64]
    __shared__ __align__(16) bf16_t Vs[64*128];   // [d][128]
    __shared__ __align__(16) bf16_t Ps[64*128];   // [q][128], XOR-swizzled

    const int tid = threadIdx.x;
    const int qt = (gridDim.x - 1) - blockIdx.x;  // heavy tiles dispatch first
    const int q0 = qt * 64;
    const int bh = blockIdx.y, b = bh >> 4, hh = bh & 15;
    const int l = tid & 63, w = tid >> 6;
    const int lr = l & 15, g = l >> 4;
    const int lk = g * 8;
    const int ktm = q0 >> 7;                 // last causal 128-key tile
    const int cnt = S - 128*(ktm + 1);       // fully-masked tail key count
    const int myq = q0 + w*16 + lr;          // q this lane holds stats for
    const int qloc = w*16 + lr;              // row in Ps

    bf16x8 qfr[2];
    {
        const bf16_t* qp = qbf + (size_t)(b*S + myq)*DD + hh*HDIM;
        qfr[0] = *(const bf16x8*)(qp + lk);
        qfr[1] = *(const bf16x8*)(qp + 32 + lk);
    }

    float m_run = (cnt > 0) ? 0.f : -3.0e38f;   // masked zeros participate
    float psum = 0.f;
    f32x4 z4 = {0.f, 0.f, 0.f, 0.f};
    f32x4 acc[4];                  // O[q = w*16 + g*4+r][d = j*16+lr]
    #pragma unroll
    for (int j = 0; j < 4; ++j) acc[j] = z4;

    const int sr = l >> 3, sc = (l & 7) * 8;

    for (int kt = 0; kt <= ktm; ++kt) {
        __syncthreads();                       // Ks/Vs free from prev iter
        const bf16_t* Kg = kbf + (size_t)(b*S + kt*128)*DD + hh*HDIM;
        #pragma unroll
        for (int it = 0; it < 4; ++it) {
            const int krow = (w*4 + it)*8 + sr;
            GLD16(Kg + (size_t)krow*DD + sc, Ks + (w*4 + it)*512);
        }
        const bf16_t* Vg = Vt + ((size_t)bh*HDIM)*S + kt*128;
        #pragma unroll
        for (int it = 0; it < 4; ++it) {
            const int drow = (w*4 + it)*4 + g;
            GLD16(Vg + (size_t)drow*S + lr*8, Vs + (w*4 + it)*512);
        }
        __syncthreads();                       // tiles staged (vmcnt drained)

        float sv[8][4];
        float mtile = -3.0e38f;
        #pragma unroll
        for (int f = 0; f < 8; ++f) {
            bf16x8 ka0 = *(const bf16x8*)&Ks[(f*16 + lr)*64 + lk];
            bf16x8 ka1 = *(const bf16x8*)&Ks[(f*16 + lr)*64 + 32 + lk];
            f32x4 t = z4;
            t = MFMA16(ka0, qfr[0], t);
            t = MFMA16(ka1, qfr[1], t);
            #pragma unroll
            for (int r = 0; r < 4; ++r) {
                const int key = kt*128 + f*16 + g*4 + r;
                float v = t[r] * 0.125f;       // HD^-0.5; zm folded into kbf
                v = (key <= myq) ? v : 0.f;
                sv[f][r] = v;
                mtile = fmaxf(mtile, v);
            }
        }
        mtile = fmaxf(mtile, __shfl_xor(mtile, 16, 64));
        mtile = fmaxf(mtile, __shfl_xor(mtile, 32, 64));
        const float m_new = fmaxf(m_run, mtile);
        const float fac = expf(m_run - m_new);
        m_run = m_new;

        float ps_t = 0.f;
        #pragma unroll
        for (int f = 0; f < 8; ++f) {
            bf16x4 pk;
            #pragma unroll
            for (int r = 0; r < 4; ++r) {
                float p = expf(sv[f][r] - m_new);
                ps_t += p;
                pk[r] = (bf16_t)p;
            }
            const int byteoff = (qloc*256 + f*32 + g*8) ^ ((lr & 7) << 4);
            *(bf16x4*)((char*)Ps + byteoff) = pk;
        }
        ps_t += __shfl_xor(ps_t, 16, 64);
        ps_t += __shfl_xor(ps_t, 32, 64);
        psum = psum * fac + ps_t;

        #pragma unroll
        for (int r = 0; r < 4; ++r) {
            const float fr_ = __shfl(fac, g*4 + r, 64);
            #pragma unroll
            for (int j = 0; j < 4; ++j) acc[j][r] *= fr_;
        }

        #pragma unroll
        for (int kk = 0; kk < 4; ++kk) {
            const int rboff = (qloc*256 + kk*64 + g*16) ^ ((lr & 7) << 4);
            bf16x8 pa = *(const bf16x8*)((char*)Ps + rboff);
            #pragma unroll
            for (int j = 0; j < 4; ++j) {
                bf16x8 vb = *(const bf16x8*)&Vs[(j*16 + lr)*128 + kk*32 + lk];
                acc[j] = MFMA16(pa, vb, acc[j]);
            }
        }
    }

    if (cnt > 0) psum += (float)cnt * expf(-m_run);

    #pragma unroll
    for (int r = 0; r < 4; ++r) {
        const float m_r  = __shfl(m_run, g*4 + r, 64);
        const float ps_r = __shfl(psum,  g*4 + r, 64);
        const float inv = 1.0f / ps_r;
        const float tailf = (cnt > 0) ? expf(-m_r) : 0.f;
        const int qrow = q0 + w*16 + g*4 + r;
        const size_t rowbase = (size_t)(b*S + qrow)*DD + hh*HDIM;
        #pragma unroll
        for (int j = 0; j < 4; ++j) {
            float val = acc[j][r];
            if (cnt > 0)
                val += tailf * vsuf[((size_t)bh*8 + ktm + 1)*64 + j*16 + lr];
            O[rowbase + j*16 + lr] = (bf16_t)(val * inv);
        }
    }
}

// ---------------------------------------------------------------------------
extern "C" void kernel_launch(void* const* d_in, const int* in_sizes, int n_in,
                              void* d_out, int out_size, void* d_ws, size_t ws_size,
                              hipStream_t stream)
{
    const int S = SEQ;
    const int B = in_sizes[0] / S;     // 2
    const int M = B * S;               // 2048
    const int BH = B * HEADS;          // 32

    const int*   x       = (const int*)  d_in[0];
    const float* tok_emb = (const float*)d_in[2];
    const float* pos_emb = (const float*)d_in[3];
    const float* rif     = (const float*)d_in[4];
    const float* rbias   = (const float*)d_in[5];
    const float* brif    = (const float*)d_in[6];
    const float* bbias   = (const float*)d_in[7];
    const float* lna     = (const float*)d_in[8];
    const float* qw      = (const float*)d_in[9];
    const float* qb      = (const float*)d_in[10];
    const float* kw      = (const float*)d_in[11];
    const float* vw      = (const float*)d_in[12];
    const float* vbias   = (const float*)d_in[13];
    const float* ow      = (const float*)d_in[14];
    const float* ob      = (const float*)d_in[15];
    const float* factor  = (const float*)d_in[16];
    const float* lnc     = (const float*)d_in[17];
    const float* w1      = (const float*)d_in[18];
    const float* b1      = (const float*)d_in[19];
    const float* w2      = (const float*)d_in[20];
    const float* b2      = (const float*)d_in[21];
    const float* lnd     = (const float*)d_in[22];

    char* ob_ = (char*)d_out;
    const size_t MiB = 1024*1024;
    float*  h      = (float*)(ob_ + 0*MiB);      // 8 MiB
    float*  h2     = (float*)(ob_ + 8*MiB);      // 8 MiB
    bf16_t* qbf    = (bf16_t*)(ob_ + 16*MiB);    // 4 MiB
    bf16_t* kbf    = (bf16_t*)(ob_ + 20*MiB);    // 4 MiB
    bf16_t* vt     = (bf16_t*)(ob_ + 24*MiB);    // 4 MiB  Vt[b][h][d][S]
    bf16_t* attno  = (bf16_t*)(ob_ + 28*MiB);    // 4 MiB
    bf16_t* m1     = (bf16_t*)(ob_ + 32*MiB);    // 16 MiB
    float*  ctab   = (float*)(ob_ + 50*MiB);     // 128 KiB
    float*  stab   = (float*)(ob_ + 51*MiB);     // 128 KiB
    float*  vsuf   = (float*)(ob_ + 52*MiB);     // 64 KiB
    bf16_t* qw_bf  = (bf16_t*)(ob_ + 64*MiB);    // 8 MiB (4 layers)
    bf16_t* kw_bf  = (bf16_t*)(ob_ + 72*MiB);
    bf16_t* vw_bf  = (bf16_t*)(ob_ + 80*MiB);
    bf16_t* ow_bf  = (bf16_t*)(ob_ + 88*MiB);
    bf16_t* w1_bf  = (bf16_t*)(ob_ + 96*MiB);    // 32 MiB
    bf16_t* w2_bf  = (bf16_t*)(ob_ + 128*MiB);   // 32 MiB -> ends 160 < 250 MiB

    bf16_t* hn      = (bf16_t*)d_ws;             // 4 MiB
    bf16_t* temb_bf = (bf16_t*)((char*)d_ws + 4*MiB);
    const bool big_ws = ws_size >= (size_t)(70*MiB);

    const long NW_D = (long)NLAYER * DD * DD;
    const long NW_F = (long)NLAYER * FFDIM * DD;
    const long NW_E = (long)NVOCAB * DD;
    cvt_kernel<<<NW_D/2048, 256, 0, stream>>>(qw, qw_bf, NW_D);
    cvt_kernel<<<NW_D/2048, 256, 0, stream>>>(kw, kw_bf, NW_D);
    cvt_kernel<<<NW_D/2048, 256, 0, stream>>>(vw, vw_bf, NW_D);
    cvt_kernel<<<NW_D/2048, 256, 0, stream>>>(ow, ow_bf, NW_D);
    cvt_kernel<<<NW_F/2048, 256, 0, stream>>>(w1, w1_bf, NW_F);
    cvt_kernel<<<NW_F/2048, 256, 0, stream>>>(w2, w2_bf, NW_F);
    if (big_ws)
        cvt_kernel<<<(NW_E+2047)/2048, 256, 0, stream>>>(tok_emb, temb_bf, NW_E);
    ropetab_kernel<<<(S*32)/256, 256, 0, stream>>>(brif, bbias, ctab, stab);

    dim3 gF(FFDIM/128,  M/128);
    dim3 gS(DD/128,     M/64);          // 64x128-tile GEMMs: 256 blocks
    dim3 gV256(NVOCAB/256, M/256);      // 125 x 8 = 1000 blocks
    dim3 gVfb(NVOCAB/128, M/128);
    dim3 gQKV(3*DD/128, M/128);
    dim3 gATT(S/64, BH);

    embed_rope_kernel<<<M, 512, 0, stream>>>(x, tok_emb, pos_emb, rif, rbias, h, S);

    for (int l = 0; l < NLAYER; ++l) {
        const size_t wo = (size_t)l * DD * DD;
        const size_t fo = (size_t)l * FFDIM * DD;
        rmsnorm_kernel<<<M, 256, 0, stream>>>(h, lna + l*DD, hn);
        qkv_gemm<<<gQKV, 256, 0, stream>>>(hn, qw_bf + wo, kw_bf + wo, vw_bf + wo,
                                           qb + l*DD, vbias + l*DD, ctab, stab,
                                           factor + l, qbf, kbf, vt, S);
        vsuf_kernel<<<BH, 256, 0, stream>>>(vt, vsuf, S);
        attn_fused<<<gATT, 256, 0, stream>>>(qbf, kbf, vt, vsuf, attno, S);
        // h2 = attno @ ow^T + ob + h
        gemm_bf_s<<<gS, 256, 0, stream>>>(attno, ow_bf + wo, ob + l*DD, h, nullptr,
                                          h2, M, DD, DD);
        rmsnorm_kernel<<<M, 256, 0, stream>>>(h2, lnc + l*DD, hn);
        gemm_bf<<<gF, 256, 0, stream>>>(hn, w1_bf + fo, b1 + l*FFDIM, nullptr, nullptr,
                                        nullptr, m1, M, FFDIM, DD, 1, 1, 0);
        // h_new = m1 @ w2^T + b2 + h2 + h   (== 2*h_old + attn + mlp)
        gemm_bf_s<<<gS, 256, 0, stream>>>(m1, w2_bf + fo, b2 + l*DD, h2, h,
                                          h, M, DD, FFDIM);
    }

    rmsnorm_kernel<<<M, 256, 0, stream>>>(h, lnd, hn);
    if (big_ws) {
        hipFuncSetAttribute((const void*)gemm256_bf,
                            hipFuncAttributeMaxDynamicSharedMemorySize, 131072);
        gemm256_bf<<<gV256, 512, 131072, stream>>>(hn, temb_bf, (float*)d_out,
                                                   M, NVOCAB);
    } else {
        gemm_bfw32<<<gVfb, 256, 0, stream>>>(hn, tok_emb, (float*)d_out, M, NVOCAB, DD);
    }
}

// Round 10
// 1226.159 us; speedup vs baseline: 1.2988x; 1.0284x over previous
//
#include <hip/hip_runtime.h>
#include <hip/hip_bf16.h>

#define DD 1024
#define HEADS 16
#define HDIM 64
#define NLAYER 4
#define FFDIM 4096
#define NVOCAB 32000
#define SEQ 1024

typedef __bf16 bf16_t;
typedef __bf16 bf16x8 __attribute__((ext_vector_type(8)));
typedef __bf16 bf16x4 __attribute__((ext_vector_type(4)));
typedef float f32x4 __attribute__((ext_vector_type(4)));

#define MFMA16(a, b, c) __builtin_amdgcn_mfma_f32_16x16x32_bf16((a), (b), (c), 0, 0, 0)

// async global->LDS, 16B per lane, dest = wave-uniform base + lane*16
#define GLD16(gp, lp) \
    __builtin_amdgcn_global_load_lds( \
        (const __attribute__((address_space(1))) void*)(gp), \
        (__attribute__((address_space(3))) void*)(lp), 16, 0, 0)

// raw barrier (no implicit vmcnt/lgkm drain) with compile-time motion fences
#define BAR() do { __builtin_amdgcn_sched_barrier(0); \
                   __builtin_amdgcn_s_barrier(); \
                   __builtin_amdgcn_sched_barrier(0); } while (0)
#define WAITVM(n) asm volatile("s_waitcnt vmcnt(" #n ")" ::: "memory")

static __device__ __forceinline__ bf16x8 pack8(float4 u, float4 v) {
    bf16x8 r;
    r[0] = (bf16_t)u.x; r[1] = (bf16_t)u.y; r[2] = (bf16_t)u.z; r[3] = (bf16_t)u.w;
    r[4] = (bf16_t)v.x; r[5] = (bf16_t)v.y; r[6] = (bf16_t)v.z; r[7] = (bf16_t)v.w;
    return r;
}

// ---------------------------------------------------------------------------
// Batched f32 -> bf16 convert: all weight tensors in ONE launch.
// Every segment's element count is a multiple of 2048 (checked on host).
// ---------------------------------------------------------------------------
struct CvtBatch {
    const float* src[7];
    bf16_t*      dst[7];
    int          blk0[7];   // starting block of each segment
    int          nseg;
};

__global__ __launch_bounds__(256) void cvt_batch(CvtBatch cb) {
    const int b = blockIdx.x;
    int s = 0;
    #pragma unroll
    for (int t = 1; t < 7; ++t)
        if (t < cb.nseg && b >= cb.blk0[t]) s = t;
    const long i = ((long)(b - cb.blk0[s]) * 256 + threadIdx.x) * 8;
    float4 a = *(const float4*)(cb.src[s] + i);
    float4 v = *(const float4*)(cb.src[s] + i + 4);
    *(bf16x8*)(cb.dst[s] + i) = pack8(a, v);
}

// ---------------------------------------------------------------------------
// Head-rope cos/sin tables: [S][32]
// ---------------------------------------------------------------------------
__global__ __launch_bounds__(256) void ropetab_kernel(
    const float* __restrict__ inv_freq, const float* __restrict__ rbias,
    float* __restrict__ ctab, float* __restrict__ stab)
{
    int idx = blockIdx.x * 256 + threadIdx.x;     // s*32 + i
    int s = idx >> 5, i = idx & 31;
    float fr = (float)s * inv_freq[i] + rbias[idx];
    ctab[idx] = cosf(fr);
    stab[idx] = sinf(fr);
}

// ---------------------------------------------------------------------------
// Embedding + decoder-level rotary
// ---------------------------------------------------------------------------
__global__ __launch_bounds__(512) void embed_rope_kernel(
    const int* __restrict__ x, const float* __restrict__ tok_emb,
    const float* __restrict__ pos_emb, const float* __restrict__ inv_freq,
    const float* __restrict__ rbias, float* __restrict__ h, int S)
{
    const int row = blockIdx.x;      // b*S + s
    const int s = row % S;
    const int i = threadIdx.x;       // 0..511 pair index
    const int tok = x[row];
    const float* e = tok_emb + (size_t)tok * DD;
    const float* p = pos_emb + (size_t)s * DD;
    float a = e[2*i]   + p[2*i];
    float b = e[2*i+1] + p[2*i+1];
    float fr = (float)s * inv_freq[i] + rbias[(size_t)s * (DD/2) + i];
    float c = cosf(fr), sn = sinf(fr);
    h[(size_t)row*DD + 2*i]   = a*c - b*sn;
    h[(size_t)row*DD + 2*i+1] = a*sn + b*c;
}

// ---------------------------------------------------------------------------
// RMSNorm with bf16 output
// ---------------------------------------------------------------------------
__global__ __launch_bounds__(256) void rmsnorm_kernel(
    const float* __restrict__ x, const float* __restrict__ w,
    bf16_t* __restrict__ y)
{
    const int row = blockIdx.x;
    const float* xr = x + (size_t)row * DD;
    float ss = 0.f;
    for (int j = threadIdx.x; j < DD; j += 256) { float v = xr[j]; ss += v*v; }
    for (int off = 32; off > 0; off >>= 1) ss += __shfl_down(ss, off, 64);
    __shared__ float r[4];
    if ((threadIdx.x & 63) == 0) r[threadIdx.x >> 6] = ss;
    __syncthreads();
    float tot = r[0] + r[1] + r[2] + r[3];
    float sc = rsqrtf(tot * (1.0f/(float)DD) + 1e-8f);
    for (int j = threadIdx.x; j < DD; j += 256)
        y[(size_t)row*DD + j] = (bf16_t)(xr[j] * sc * w[j]);
}

// ---------------------------------------------------------------------------
// bf16 MFMA GEMM 128x128, reg-prefetch schedule (unchanged, proven).
// ---------------------------------------------------------------------------
__global__ __launch_bounds__(256) void gemm_bf(
    const bf16_t* __restrict__ A, const bf16_t* __restrict__ W,
    const float* __restrict__ bias, const float* __restrict__ add1,
    const float* __restrict__ add2, float* __restrict__ C,
    bf16_t* __restrict__ Cb,
    int M, int N, int K, int relu, int mode, int swz)
{
    __shared__ __align__(16) bf16_t As[128*64];
    __shared__ __align__(16) bf16_t Bs[128*64];
    const int tid = threadIdx.x;
    int bx = blockIdx.x, by = blockIdx.y;
    if (swz) {
        const int nbx = gridDim.x, nby = gridDim.y;
        const int nwg = nbx * nby;             // divisible by 8
        const int lin = by * nbx + bx;
        const int wg  = (lin & 7) * (nwg >> 3) + (lin >> 3);
        bx = wg / nby;                         // n-major: same-n blocks adjacent
        by = wg % nby;
    }
    const int m0 = by * 128, n0 = bx * 128;
    const int l = tid & 63, w = tid >> 6;
    const int wr = (w >> 1) * 64, wc = (w & 1) * 64;
    const int lr = l & 15, lk = (l >> 4) * 8;

    const int srow = l >> 3, scol = (l & 7) * 8;
    const bf16_t* Ag = A + (size_t)(m0 + w*32 + srow) * K + scol;
    const bf16_t* Wg = W + (size_t)(n0 + w*32 + srow) * K + scol;

    f32x4 z4 = {0.f, 0.f, 0.f, 0.f};
    f32x4 acc[4][4];
    #pragma unroll
    for (int i = 0; i < 4; ++i)
        #pragma unroll
        for (int j = 0; j < 4; ++j) acc[i][j] = z4;

    #pragma unroll
    for (int it = 0; it < 4; ++it) {
        GLD16(Ag + (size_t)(it*8)*K, As + (w*4 + it)*512);
        GLD16(Wg + (size_t)(it*8)*K, Bs + (w*4 + it)*512);
    }

    for (int k0 = 0; k0 < K; k0 += 64) {
        __syncthreads();                       // B1: tile landed
        bf16x8 afr[8], bfr[8];
        #pragma unroll
        for (int kk = 0; kk < 2; ++kk)
            #pragma unroll
            for (int i = 0; i < 4; ++i) {
                afr[kk*4+i] = *(const bf16x8*)&As[(wr + i*16 + lr)*64 + kk*32 + lk];
                bfr[kk*4+i] = *(const bf16x8*)&Bs[(wc + i*16 + lr)*64 + kk*32 + lk];
            }
        __syncthreads();                       // B2: reads done, LDS free
        if (k0 + 64 < K) {
            #pragma unroll
            for (int it = 0; it < 4; ++it) {
                GLD16(Ag + (size_t)(it*8)*K + k0 + 64, As + (w*4 + it)*512);
                GLD16(Wg + (size_t)(it*8)*K + k0 + 64, Bs + (w*4 + it)*512);
            }
        }
        #pragma unroll
        for (int kk = 0; kk < 2; ++kk)
            #pragma unroll
            for (int i = 0; i < 4; ++i)
                #pragma unroll
                for (int j = 0; j < 4; ++j)
                    acc[i][j] = MFMA16(afr[kk*4+i], bfr[kk*4+j], acc[i][j]);
    }

    #pragma unroll
    for (int i = 0; i < 4; ++i) {
        #pragma unroll
        for (int j = 0; j < 4; ++j) {
            const int col  = n0 + wc + j*16 + lr;
            const int row0 = m0 + wr + i*16 + (l >> 4)*4;
            const float bv = bias ? bias[col] : 0.f;
            #pragma unroll
            for (int r2 = 0; r2 < 4; ++r2) {
                const int row = row0 + r2;
                float val = acc[i][j][r2] + bv;
                if (add1) val += add1[(size_t)row*N + col];
                if (add2) val += add2[(size_t)row*N + col];
                if (relu) val = fmaxf(val, 0.f);
                if (mode == 0) C[(size_t)row*N + col] = val;
                else           Cb[(size_t)row*N + col] = (bf16_t)val;
            }
        }
    }
}

// ---------------------------------------------------------------------------
// Small-tile GEMM 64x128 (grid-doubling for N=1024 shapes: o-proj, mlp2).
// ---------------------------------------------------------------------------
__global__ __launch_bounds__(256) void gemm_bf_s(
    const bf16_t* __restrict__ A, const bf16_t* __restrict__ W,
    const float* __restrict__ bias, const float* __restrict__ add1,
    const float* __restrict__ add2, float* __restrict__ C,
    int M, int N, int K)
{
    __shared__ __align__(16) bf16_t As[64*64];
    __shared__ __align__(16) bf16_t Bs[128*64];
    const int tid = threadIdx.x;
    const int m0 = blockIdx.y * 64, n0 = blockIdx.x * 128;
    const int l = tid & 63, w = tid >> 6;
    const int wr = (w >> 1) * 32, wc = (w & 1) * 64;
    const int lr = l & 15, lk = (l >> 4) * 8;

    const int srow = l >> 3, scol = (l & 7) * 8;
    const bf16_t* Ag = A + (size_t)(m0 + w*16 + srow) * K + scol;   // 2 slots/wave
    const bf16_t* Wg = W + (size_t)(n0 + w*32 + srow) * K + scol;   // 4 slots/wave

    f32x4 z4 = {0.f, 0.f, 0.f, 0.f};
    f32x4 acc[2][4];
    #pragma unroll
    for (int i = 0; i < 2; ++i)
        #pragma unroll
        for (int j = 0; j < 4; ++j) acc[i][j] = z4;

    #pragma unroll
    for (int it = 0; it < 2; ++it)
        GLD16(Ag + (size_t)(it*8)*K, As + (w*2 + it)*512);
    #pragma unroll
    for (int it = 0; it < 4; ++it)
        GLD16(Wg + (size_t)(it*8)*K, Bs + (w*4 + it)*512);

    for (int k0 = 0; k0 < K; k0 += 64) {
        __syncthreads();                       // B1: tile landed
        bf16x8 afr[4], bfr[8];
        #pragma unroll
        for (int kk = 0; kk < 2; ++kk) {
            #pragma unroll
            for (int i = 0; i < 2; ++i)
                afr[kk*2+i] = *(const bf16x8*)&As[(wr + i*16 + lr)*64 + kk*32 + lk];
            #pragma unroll
            for (int j = 0; j < 4; ++j)
                bfr[kk*4+j] = *(const bf16x8*)&Bs[(wc + j*16 + lr)*64 + kk*32 + lk];
        }
        __syncthreads();                       // B2: reads done, LDS free
        if (k0 + 64 < K) {
            #pragma unroll
            for (int it = 0; it < 2; ++it)
                GLD16(Ag + (size_t)(it*8)*K + k0 + 64, As + (w*2 + it)*512);
            #pragma unroll
            for (int it = 0; it < 4; ++it)
                GLD16(Wg + (size_t)(it*8)*K + k0 + 64, Bs + (w*4 + it)*512);
        }
        #pragma unroll
        for (int kk = 0; kk < 2; ++kk)
            #pragma unroll
            for (int i = 0; i < 2; ++i)
                #pragma unroll
                for (int j = 0; j < 4; ++j)
                    acc[i][j] = MFMA16(afr[kk*2+i], bfr[kk*4+j], acc[i][j]);
    }

    #pragma unroll
    for (int i = 0; i < 2; ++i) {
        #pragma unroll
        for (int j = 0; j < 4; ++j) {
            const int col  = n0 + wc + j*16 + lr;
            const int row0 = m0 + wr + i*16 + (l >> 4)*4;
            const float bv = bias ? bias[col] : 0.f;
            #pragma unroll
            for (int r2 = 0; r2 < 4; ++r2) {
                const int row = row0 + r2;
                float val = acc[i][j][r2] + bv;
                if (add1) val += add1[(size_t)row*N + col];
                if (add2) val += add2[(size_t)row*N + col];
                C[(size_t)row*N + col] = val;
            }
        }
    }
}

// ---------------------------------------------------------------------------
// 256x256 8-phase GEMM (T2 swizzle + T3/T4 counted vmcnt + T5 setprio).
// K fixed = 1024 (logits). 512 thr / 8 waves (2M x 4N), per-wave 128x64.
// LDS 128 KiB dynamic: [buf][A|B][256][64] bf16, double-buffered.
// FULL 3-bit swizzle: elem col ^= ((row bits 1-3))<<3 — per 8-lane issue
// group each 16B slot gets exactly 2 lanes (2-way = free, m136).
// Stage source pre-permuted with the same involution (rule 21).
// ---------------------------------------------------------------------------
__global__ __launch_bounds__(512, 2) void gemm256_bf(
    const bf16_t* __restrict__ A, const bf16_t* __restrict__ W,
    float* __restrict__ C, int M, int N)
{
    extern __shared__ __align__(16) char dynsm[];
    bf16_t* TILE = (bf16_t*)dynsm;
    const int tid = threadIdx.x;
    // n-major XCD-chunked swizzle (nwg = 125*8 = 1000, %8 == 0)
    const int nbx = gridDim.x, nby = gridDim.y;
    const int nwg = nbx * nby;
    const int lin = blockIdx.y * nbx + blockIdx.x;
    const int wg  = (lin & 7) * (nwg >> 3) + (lin >> 3);
    const int n0 = (wg / nby) * 256, m0 = (wg % nby) * 256;

    const int l = tid & 63, w = tid >> 6;
    const int wm = w >> 2, wn = w & 3;
    const int lr = l & 15, lg = l >> 4;
    const int swzr = ((l >> 1) & 7) << 3;        // read-side swizzle (elems), row bits 1-3 = lr bits 1-3
    const int srow = tid >> 3;                   // 0..63 staging row within s-half
    const int scolE = ((tid & 7) * 8) ^ (((tid >> 4) & 7) << 3);  // pre-swizzled src col (elems)

    const bf16_t* Ap = A + (size_t)m0 * 1024;
    const bf16_t* Wp = W + (size_t)n0 * 1024;

    auto STG = [&](int buf, int isB, int half, int k0) {
        const bf16_t* G = isB ? Wp : Ap;
        bf16_t* L = TILE + (buf*2 + isB)*16384 + half*8192 + w*512;
        const int rbase = half*128 + srow;
        GLD16(G + (size_t)rbase*1024 + k0 + scolE,          L);
        GLD16(G + (size_t)(rbase + 64)*1024 + k0 + scolE,   L + 4096);
    };
    auto RD_A = [&](int buf, int fi, int kk) -> bf16x8 {
        const int row = wm*128 + fi*16 + lr;
        return *(const bf16x8*)&TILE[(buf*2)*16384 + row*64 + ((kk*32 + lg*8) ^ swzr)];
    };
    auto RD_B = [&](int buf, int fj, int kk) -> bf16x8 {
        const int row = wn*64 + fj*16 + lr;
        return *(const bf16x8*)&TILE[(buf*2 + 1)*16384 + row*64 + ((kk*32 + lg*8) ^ swzr)];
    };

    f32x4 z4 = {0.f, 0.f, 0.f, 0.f};
    f32x4 acc[8][4];
    #pragma unroll
    for (int i = 0; i < 8; ++i)
        #pragma unroll
        for (int j = 0; j < 4; ++j) acc[i][j] = z4;
    bf16x8 bfr[4][2];

#define DO_PHASE(BUF, P, STAGE_STMT, TAIL_STMT) do {                          \
    bf16x8 a0_0 = RD_A(BUF, 2*(P), 0),   a0_1 = RD_A(BUF, 2*(P), 1);          \
    bf16x8 a1_0 = RD_A(BUF, 2*(P)+1, 0), a1_1 = RD_A(BUF, 2*(P)+1, 1);        \
    if ((P) == 0) {                                                           \
        _Pragma("unroll")                                                     \
        for (int fj = 0; fj < 4; ++fj) {                                      \
            bfr[fj][0] = RD_B(BUF, fj, 0);                                    \
            bfr[fj][1] = RD_B(BUF, fj, 1);                                    \
        }                                                                     \
    }                                                                         \
    STAGE_STMT;                                                               \
    BAR();                                                                    \
    __builtin_amdgcn_s_setprio(1);                                            \
    _Pragma("unroll")                                                         \
    for (int fj = 0; fj < 4; ++fj) {                                          \
        acc[2*(P)][fj]   = MFMA16(a0_0, bfr[fj][0], acc[2*(P)][fj]);          \
        acc[2*(P)][fj]   = MFMA16(a0_1, bfr[fj][1], acc[2*(P)][fj]);          \
        acc[2*(P)+1][fj] = MFMA16(a1_0, bfr[fj][0], acc[2*(P)+1][fj]);        \
        acc[2*(P)+1][fj] = MFMA16(a1_1, bfr[fj][1], acc[2*(P)+1][fj]);        \
    }                                                                         \
    __builtin_amdgcn_s_setprio(0);                                            \
    TAIL_STMT;                                                                \
    BAR();                                                                    \
} while (0)

    // prologue: t0 full + t1.B; force t0 landed (t1.B in flight)
    STG(0, 0, 0, 0);  STG(0, 0, 1, 0);
    STG(0, 1, 0, 0);  STG(0, 1, 1, 0);
    STG(1, 1, 0, 64); STG(1, 1, 1, 64);
    WAITVM(4);
    BAR();

    #pragma unroll 1
    for (int itr = 0; itr < 8; ++itr) {
        const int k_o  = (2*itr + 1) * 64;
        const int k_e2 = (2*itr + 2) * 64;
        const int k_o2 = (2*itr + 3) * 64;
        const bool more = (itr < 7);
        // tile even (buf0), phases 1-4
        DO_PHASE(0, 0, STG(1, 0, 0, k_o), ;);
        DO_PHASE(0, 1, STG(1, 0, 1, k_o), ;);
        DO_PHASE(0, 2, if (more) STG(0, 1, 0, k_e2), ;);
        DO_PHASE(0, 3, if (more) STG(0, 1, 1, k_e2),
                 if (more) { WAITVM(4); } else { WAITVM(0); });
        // tile odd (buf1), phases 5-8
        DO_PHASE(1, 0, if (more) STG(0, 0, 0, k_e2), ;);
        DO_PHASE(1, 1, if (more) STG(0, 0, 1, k_e2), ;);
        DO_PHASE(1, 2, if (more) STG(1, 1, 0, k_o2), ;);
        DO_PHASE(1, 3, if (more) STG(1, 1, 1, k_o2),
                 if (more) { WAITVM(4); });
    }
#undef DO_PHASE

    #pragma unroll
    for (int i = 0; i < 8; ++i) {
        #pragma unroll
        for (int j = 0; j < 4; ++j) {
            const int col  = n0 + wn*64 + j*16 + lr;
            const int row0 = m0 + wm*128 + i*16 + lg*4;
            #pragma unroll
            for (int r2 = 0; r2 < 4; ++r2)
                C[(size_t)(row0 + r2)*N + col] = acc[i][j][r2];
        }
    }
}

// ---------------------------------------------------------------------------
// Fallback logits GEMM (A bf16 via gload_lds, W f32 reg-staged). Unchanged.
// ---------------------------------------------------------------------------
__global__ __launch_bounds__(256) void gemm_bfw32(
    const bf16_t* __restrict__ A, const float* __restrict__ W,
    float* __restrict__ C, int M, int N, int K)
{
    __shared__ __align__(16) bf16_t As[128*64];
    __shared__ __align__(16) bf16_t Bs[128*64];
    const int tid = threadIdx.x;
    const int m0 = blockIdx.y * 128, n0 = blockIdx.x * 128;
    const int l = tid & 63, w = tid >> 6;
    const int wr = (w >> 1) * 64, wc = (w & 1) * 64;
    const int lr = l & 15, lk = (l >> 4) * 8;
    const int srow = l >> 3, scol = (l & 7) * 8;
    const bf16_t* Ag = A + (size_t)(m0 + w*32 + srow) * K + scol;
    const int r = tid >> 1, half = (tid & 1) * 32;
    const float* Wp = W + (size_t)(n0 + r) * K + half;

    f32x4 z4 = {0.f, 0.f, 0.f, 0.f};
    f32x4 acc[4][4];
    #pragma unroll
    for (int i = 0; i < 4; ++i)
        #pragma unroll
        for (int j = 0; j < 4; ++j) acc[i][j] = z4;

    for (int k0 = 0; k0 < K; k0 += 64) {
        float4 wv[8];
        #pragma unroll
        for (int j = 0; j < 8; ++j) wv[j] = *(const float4*)(Wp + k0 + 4*j);
        __syncthreads();
        #pragma unroll
        for (int it = 0; it < 4; ++it)
            GLD16(Ag + (size_t)(it*8)*K + k0, As + (w*4 + it)*512);
        #pragma unroll
        for (int j = 0; j < 4; ++j)
            *(bf16x8*)&Bs[r*64 + half + 8*j] = pack8(wv[2*j], wv[2*j+1]);
        __syncthreads();
        #pragma unroll
        for (int kk = 0; kk < 2; ++kk) {
            bf16x8 afr[4], bfr[4];
            #pragma unroll
            for (int i = 0; i < 4; ++i)
                afr[i] = *(const bf16x8*)&As[(wr + i*16 + lr)*64 + kk*32 + lk];
            #pragma unroll
            for (int j = 0; j < 4; ++j)
                bfr[j] = *(const bf16x8*)&Bs[(wc + j*16 + lr)*64 + kk*32 + lk];
            #pragma unroll
            for (int i = 0; i < 4; ++i)
                #pragma unroll
                for (int j = 0; j < 4; ++j)
                    acc[i][j] = MFMA16(afr[i], bfr[j], acc[i][j]);
        }
    }
    #pragma unroll
    for (int i = 0; i < 4; ++i)
        #pragma unroll
        for (int j = 0; j < 4; ++j) {
            const int col  = n0 + wc + j*16 + lr;
            const int row0 = m0 + wr + i*16 + (l >> 4)*4;
            #pragma unroll
            for (int r2 = 0; r2 < 4; ++r2)
                C[(size_t)(row0 + r2)*N + col] = acc[i][j][r2];
        }
}

// ---------------------------------------------------------------------------
// Fused QKV GEMM (unchanged from round 8: scaled_zero folded into kbf,
// coalesced Vt store via LDS transpose).
// ---------------------------------------------------------------------------
__global__ __launch_bounds__(256) void qkv_gemm(
    const bf16_t* __restrict__ A, const bf16_t* __restrict__ Wq,
    const bf16_t* __restrict__ Wk, const bf16_t* __restrict__ Wv,
    const float* __restrict__ qb, const float* __restrict__ vbias,
    const float* __restrict__ ctab, const float* __restrict__ stab,
    const float* __restrict__ fptr,
    bf16_t* __restrict__ qbf, bf16_t* __restrict__ kbf,
    bf16_t* __restrict__ vt, int S)
{
    __shared__ __align__(16) bf16_t smem[128*134];
    bf16_t* As = smem;
    bf16_t* Bs = smem + 8192;
    const int tid = threadIdx.x;
    const int seg = blockIdx.x >> 3;              // 0=q 1=k 2=v
    const int n0  = (blockIdx.x & 7) * 128;       // col within segment
    const int m0  = blockIdx.y * 128;
    const bf16_t* W = (seg == 0) ? Wq : (seg == 1) ? Wk : Wv;
    const int K = DD;
    const int l = tid & 63, w = tid >> 6;
    const int wr = (w >> 1) * 64, wc = (w & 1) * 64;
    const int lr = l & 15, lk = (l >> 4) * 8;
    const int g4 = l >> 4;

    const int srow = l >> 3, scol = (l & 7) * 8;
    const bf16_t* Ag = A + (size_t)(m0 + w*32 + srow) * K + scol;
    const bf16_t* Wg = W + (size_t)(n0 + w*32 + srow) * K + scol;

    f32x4 z4 = {0.f, 0.f, 0.f, 0.f};
    f32x4 acc[4][4];
    #pragma unroll
    for (int i = 0; i < 4; ++i)
        #pragma unroll
        for (int j = 0; j < 4; ++j) acc[i][j] = z4;

    #pragma unroll
    for (int it = 0; it < 4; ++it) {
        GLD16(Ag + (size_t)(it*8)*K, As + (w*4 + it)*512);
        GLD16(Wg + (size_t)(it*8)*K, Bs + (w*4 + it)*512);
    }

    for (int k0 = 0; k0 < K; k0 += 64) {
        __syncthreads();
        bf16x8 afr[8], bfr[8];
        #pragma unroll
        for (int kk = 0; kk < 2; ++kk)
            #pragma unroll
            for (int i = 0; i < 4; ++i) {
                afr[kk*4+i] = *(const bf16x8*)&As[(wr + i*16 + lr)*64 + kk*32 + lk];
                bfr[kk*4+i] = *(const bf16x8*)&Bs[(wc + i*16 + lr)*64 + kk*32 + lk];
            }
        __syncthreads();
        if (k0 + 64 < K) {
            #pragma unroll
            for (int it = 0; it < 4; ++it) {
                GLD16(Ag + (size_t)(it*8)*K + k0 + 64, As + (w*4 + it)*512);
                GLD16(Wg + (size_t)(it*8)*K + k0 + 64, Bs + (w*4 + it)*512);
            }
        }
        #pragma unroll
        for (int kk = 0; kk < 2; ++kk)
            #pragma unroll
            for (int i = 0; i < 4; ++i)
                #pragma unroll
                for (int j = 0; j < 4; ++j)
                    acc[i][j] = MFMA16(afr[kk*4+i], bfr[kk*4+j], acc[i][j]);
    }

    float zf = 0.f;
    if (seg == 1) {
        float f = fptr[0];
        float sp = (f > 20.f) ? f : log1pf(expf(f));
        zf = fminf(fmaxf(sp, 1e-5f), 0.1f);
    }

    #pragma unroll
    for (int i = 0; i < 4; ++i) {
        float ov[4][4];
        #pragma unroll
        for (int j = 0; j < 4; ++j) {
            const int col = n0 + wc + j*16 + lr;          // 0..1023 within seg
            const float bv = (seg == 0) ? qb[col] : (seg == 2) ? vbias[col] : 0.f;
            const int d  = col & 63;
            const int pi = d >> 1;
            #pragma unroll
            for (int r2 = 0; r2 < 4; ++r2) {
                const int row = m0 + wr + i*16 + g4*4 + r2;
                const int s  = row & (SEQ - 1);
                float val = acc[i][j][r2] + bv;
                if (seg < 2) {
                    float partner = __shfl_xor(val, 1, 64);
                    float c  = ctab[s*32 + pi];
                    float sn = stab[s*32 + pi];
                    val = ((d & 1) == 0) ? (val*c - partner*sn)
                                         : (partner*sn + val*c);
                }
                ov[j][r2] = val;
            }
        }
        if (seg == 1) {
            #pragma unroll
            for (int r2 = 0; r2 < 4; ++r2) {
                float z0 = __shfl(ov[0][r2], (l & 48), 64);
                float zr = (z0 == 0.0f) ? zf : 1.0f;
                #pragma unroll
                for (int j = 0; j < 4; ++j) ov[j][r2] *= zr;
            }
        }
        #pragma unroll
        for (int j = 0; j < 4; ++j) {
            const int col = n0 + wc + j*16 + lr;
            #pragma unroll
            for (int r2 = 0; r2 < 4; ++r2) {
                const int row = m0 + wr + i*16 + g4*4 + r2;
                if (seg == 0)      qbf[(size_t)row*DD + col] = (bf16_t)ov[j][r2];
                else if (seg == 1) kbf[(size_t)row*DD + col] = (bf16_t)ov[j][r2];
                else smem[(col - n0)*134 + (row - m0)] = (bf16_t)ov[j][r2];
            }
        }
    }

    if (seg == 2) {
        __syncthreads();          // tr complete
        const int bb2 = m0 >> 10, s0 = m0 & (SEQ - 1);
        const int d2 = tid >> 1, sh = (tid & 1) * 64;
        const int hh2 = (n0 >> 6) + (d2 >> 6);
        const int dd2 = d2 & 63;
        bf16_t* dst = vt + ((size_t)(bb2*HEADS + hh2)*HDIM + dd2)*S + s0 + sh;
        const bf16_t* srcp = smem + d2*134 + sh;
        #pragma unroll
        for (int k2 = 0; k2 < 8; ++k2)
            *(bf16x8*)(dst + k2*8) = *(const bf16x8*)(srcp + k2*8);
    }
}

// ---------------------------------------------------------------------------
// Fused flash attention. NEW: per-wave redundant causal-tail sum of Vt
// (replaces the vsuf kernel; lane l holds tail-sum for d=l, __shfl to use).
// Heavy-q blocks have short tails -> improves load balance.
// ---------------------------------------------------------------------------
__global__ __launch_bounds__(256) void attn_fused(
    const bf16_t* __restrict__ qbf, const bf16_t* __restrict__ kbf,
    const bf16_t* __restrict__ Vt, bf16_t* __restrict__ O, int S)
{
    __shared__ __align__(16) bf16_t Ks[128*64];   // [k][64]
    __shared__ __align__(16) bf16_t Vs[64*128];   // [d][128]
    __shared__ __align__(16) bf16_t Ps[64*128];   // [q][128], XOR-swizzled

    const int tid = threadIdx.x;
    const int qt = (gridDim.x - 1) - blockIdx.x;  // heavy tiles dispatch first
    const int q0 = qt * 64;
    const int bh = blockIdx.y, b = bh >> 4, hh = bh & 15;
    const int l = tid & 63, w = tid >> 6;
    const int lr = l & 15, g = l >> 4;
    const int lk = g * 8;
    const int ktm = q0 >> 7;                 // last causal 128-key tile
    const int cnt = S - 128*(ktm + 1);       // fully-masked tail key count
    const int myq = q0 + w*16 + lr;          // q this lane holds stats for
    const int qloc = w*16 + lr;              // row in Ps

    bf16x8 qfr[2];
    {
        const bf16_t* qp = qbf + (size_t)(b*S + myq)*DD + hh*HDIM;
        qfr[0] = *(const bf16x8*)(qp + lk);
        qfr[1] = *(const bf16x8*)(qp + 32 + lk);
    }

    float m_run = (cnt > 0) ? 0.f : -3.0e38f;   // masked zeros participate
    float psum = 0.f;
    f32x4 z4 = {0.f, 0.f, 0.f, 0.f};
    f32x4 acc[4];                  // O[q = w*16 + g*4+r][d = j*16+lr]
    #pragma unroll
    for (int j = 0; j < 4; ++j) acc[j] = z4;

    const int sr = l >> 3, sc = (l & 7) * 8;

    for (int kt = 0; kt <= ktm; ++kt) {
        __syncthreads();                       // Ks/Vs free from prev iter
        const bf16_t* Kg = kbf + (size_t)(b*S + kt*128)*DD + hh*HDIM;
        #pragma unroll
        for (int it = 0; it < 4; ++it) {
            const int krow = (w*4 + it)*8 + sr;
            GLD16(Kg + (size_t)krow*DD + sc, Ks + (w*4 + it)*512);
        }
        const bf16_t* Vg = Vt + ((size_t)bh*HDIM)*S + kt*128;
        #pragma unroll
        for (int it = 0; it < 4; ++it) {
            const int drow = (w*4 + it)*4 + g;
            GLD16(Vg + (size_t)drow*S + lr*8, Vs + (w*4 + it)*512);
        }
        __syncthreads();                       // tiles staged (vmcnt drained)

        float sv[8][4];
        float mtile = -3.0e38f;
        #pragma unroll
        for (int f = 0; f < 8; ++f) {
            bf16x8 ka0 = *(const bf16x8*)&Ks[(f*16 + lr)*64 + lk];
            bf16x8 ka1 = *(const bf16x8*)&Ks[(f*16 + lr)*64 + 32 + lk];
            f32x4 t = z4;
            t = MFMA16(ka0, qfr[0], t);
            t = MFMA16(ka1, qfr[1], t);
            #pragma unroll
            for (int r = 0; r < 4; ++r) {
                const int key = kt*128 + f*16 + g*4 + r;
                float v = t[r] * 0.125f;       // HD^-0.5; zm folded into kbf
                v = (key <= myq) ? v : 0.f;
                sv[f][r] = v;
                mtile = fmaxf(mtile, v);
            }
        }
        mtile = fmaxf(mtile, __shfl_xor(mtile, 16, 64));
        mtile = fmaxf(mtile, __shfl_xor(mtile, 32, 64));
        const float m_new = fmaxf(m_run, mtile);
        const float fac = expf(m_run - m_new);
        m_run = m_new;

        float ps_t = 0.f;
        #pragma unroll
        for (int f = 0; f < 8; ++f) {
            bf16x4 pk;
            #pragma unroll
            for (int r = 0; r < 4; ++r) {
                float p = expf(sv[f][r] - m_new);
                ps_t += p;
                pk[r] = (bf16_t)p;
            }
            const int byteoff = (qloc*256 + f*32 + g*8) ^ ((lr & 7) << 4);
            *(bf16x4*)((char*)Ps + byteoff) = pk;
        }
        ps_t += __shfl_xor(ps_t, 16, 64);
        ps_t += __shfl_xor(ps_t, 32, 64);
        psum = psum * fac + ps_t;

        #pragma unroll
        for (int r = 0; r < 4; ++r) {
            const float fr_ = __shfl(fac, g*4 + r, 64);
            #pragma unroll
            for (int j = 0; j < 4; ++j) acc[j][r] *= fr_;
        }

        #pragma unroll
        for (int kk = 0; kk < 4; ++kk) {
            const int rboff = (qloc*256 + kk*64 + g*16) ^ ((lr & 7) << 4);
            bf16x8 pa = *(const bf16x8*)((char*)Ps + rboff);
            #pragma unroll
            for (int j = 0; j < 4; ++j) {
                bf16x8 vb = *(const bf16x8*)&Vs[(j*16 + lr)*128 + kk*32 + lk];
                acc[j] = MFMA16(pa, vb, acc[j]);
            }
        }
    }

    // causal tail: sum_{k in tail} Vt[bh][d][k] per wave (lane l -> d=l)
    float vtail = 0.f;
    if (cnt > 0) {
        psum += (float)cnt * expf(-m_run);
        const bf16_t* vp = Vt + ((size_t)bh*HDIM + l)*S + 128*(ktm + 1);
        for (int k = 0; k < cnt; k += 8) {
            bf16x8 v = *(const bf16x8*)(vp + k);
            #pragma unroll
            for (int e = 0; e < 8; ++e) vtail += (float)v[e];
        }
    }

    #pragma unroll
    for (int r = 0; r < 4; ++r) {
        const float m_r  = __shfl(m_run, g*4 + r, 64);
        const float ps_r = __shfl(psum,  g*4 + r, 64);
        const float inv = 1.0f / ps_r;
        const float tailf = (cnt > 0) ? expf(-m_r) : 0.f;
        const int qrow = q0 + w*16 + g*4 + r;
        const size_t rowbase = (size_t)(b*S + qrow)*DD + hh*HDIM;
        #pragma unroll
        for (int j = 0; j < 4; ++j) {
            const float vt_j = __shfl(vtail, j*16 + lr, 64);
            float val = acc[j][r];
            if (cnt > 0) val += tailf * vt_j;
            O[rowbase + j*16 + lr] = (bf16_t)(val * inv);
        }
    }
}

// ---------------------------------------------------------------------------
extern "C" void kernel_launch(void* const* d_in, const int* in_sizes, int n_in,
                              void* d_out, int out_size, void* d_ws, size_t ws_size,
                              hipStream_t stream)
{
    const int S = SEQ;
    const int B = in_sizes[0] / S;     // 2
    const int M = B * S;               // 2048
    const int BH = B * HEADS;          // 32

    const int*   x       = (const int*)  d_in[0];
    const float* tok_emb = (const float*)d_in[2];
    const float* pos_emb = (const float*)d_in[3];
    const float* rif     = (const float*)d_in[4];
    const float* rbias   = (const float*)d_in[5];
    const float* brif    = (const float*)d_in[6];
    const float* bbias   = (const float*)d_in[7];
    const float* lna     = (const float*)d_in[8];
    const float* qw      = (const float*)d_in[9];
    const float* qb      = (const float*)d_in[10];
    const float* kw      = (const float*)d_in[11];
    const float* vw      = (const float*)d_in[12];
    const float* vbias   = (const float*)d_in[13];
    const float* ow      = (const float*)d_in[14];
    const float* ob      = (const float*)d_in[15];
    const float* factor  = (const float*)d_in[16];
    const float* lnc     = (const float*)d_in[17];
    const float* w1      = (const float*)d_in[18];
    const float* b1      = (const float*)d_in[19];
    const float* w2      = (const float*)d_in[20];
    const float* b2      = (const float*)d_in[21];
    const float* lnd     = (const float*)d_in[22];

    char* ob_ = (char*)d_out;
    const size_t MiB = 1024*1024;
    float*  h      = (float*)(ob_ + 0*MiB);      // 8 MiB
    float*  h2     = (float*)(ob_ + 8*MiB);      // 8 MiB
    bf16_t* qbf    = (bf16_t*)(ob_ + 16*MiB);    // 4 MiB
    bf16_t* kbf    = (bf16_t*)(ob_ + 20*MiB);    // 4 MiB
    bf16_t* vt     = (bf16_t*)(ob_ + 24*MiB);    // 4 MiB  Vt[b][h][d][S]
    bf16_t* attno  = (bf16_t*)(ob_ + 28*MiB);    // 4 MiB
    bf16_t* m1     = (bf16_t*)(ob_ + 32*MiB);    // 16 MiB
    float*  ctab   = (float*)(ob_ + 50*MiB);     // 128 KiB
    float*  stab   = (float*)(ob_ + 51*MiB);     // 128 KiB
    bf16_t* qw_bf  = (bf16_t*)(ob_ + 64*MiB);    // 8 MiB (4 layers)
    bf16_t* kw_bf  = (bf16_t*)(ob_ + 72*MiB);
    bf16_t* vw_bf  = (bf16_t*)(ob_ + 80*MiB);
    bf16_t* ow_bf  = (bf16_t*)(ob_ + 88*MiB);
    bf16_t* w1_bf  = (bf16_t*)(ob_ + 96*MiB);    // 32 MiB
    bf16_t* w2_bf  = (bf16_t*)(ob_ + 128*MiB);   // 32 MiB -> ends 160 < 250 MiB

    bf16_t* hn      = (bf16_t*)d_ws;             // 4 MiB
    bf16_t* temb_bf = (bf16_t*)((char*)d_ws + 4*MiB);
    const bool big_ws = ws_size >= (size_t)(70*MiB);

    // --- single batched weight conversion (all counts % 2048 == 0) ---
    {
        CvtBatch cb;
        const float* srcs[7] = {qw, kw, vw, ow, w1, w2, tok_emb};
        bf16_t*      dsts[7] = {qw_bf, kw_bf, vw_bf, ow_bf, w1_bf, w2_bf, temb_bf};
        const long   ns[7]   = {(long)NLAYER*DD*DD, (long)NLAYER*DD*DD,
                                (long)NLAYER*DD*DD, (long)NLAYER*DD*DD,
                                (long)NLAYER*FFDIM*DD, (long)NLAYER*FFDIM*DD,
                                (long)NVOCAB*DD};
        int nseg = big_ws ? 7 : 6;
        int acc = 0;
        for (int s = 0; s < 7; ++s) {
            cb.src[s] = srcs[s]; cb.dst[s] = dsts[s];
            cb.blk0[s] = acc;
            if (s < nseg) acc += (int)(ns[s] / 2048);
        }
        cb.nseg = nseg;
        cvt_batch<<<acc, 256, 0, stream>>>(cb);
    }
    ropetab_kernel<<<(S*32)/256, 256, 0, stream>>>(brif, bbias, ctab, stab);

    dim3 gF(FFDIM/128,  M/128);
    dim3 gS(DD/128,     M/64);          // 64x128-tile GEMMs: 256 blocks
    dim3 gV256(NVOCAB/256, M/256);      // 125 x 8 = 1000 blocks
    dim3 gVfb(NVOCAB/128, M/128);
    dim3 gQKV(3*DD/128, M/128);
    dim3 gATT(S/64, BH);

    embed_rope_kernel<<<M, 512, 0, stream>>>(x, tok_emb, pos_emb, rif, rbias, h, S);

    for (int l = 0; l < NLAYER; ++l) {
        const size_t wo = (size_t)l * DD * DD;
        const size_t fo = (size_t)l * FFDIM * DD;
        rmsnorm_kernel<<<M, 256, 0, stream>>>(h, lna + l*DD, hn);
        qkv_gemm<<<gQKV, 256, 0, stream>>>(hn, qw_bf + wo, kw_bf + wo, vw_bf + wo,
                                           qb + l*DD, vbias + l*DD, ctab, stab,
                                           factor + l, qbf, kbf, vt, S);
        attn_fused<<<gATT, 256, 0, stream>>>(qbf, kbf, vt, attno, S);
        // h2 = attno @ ow^T + ob + h
        gemm_bf_s<<<gS, 256, 0, stream>>>(attno, ow_bf + wo, ob + l*DD, h, nullptr,
                                          h2, M, DD, DD);
        rmsnorm_kernel<<<M, 256, 0, stream>>>(h2, lnc + l*DD, hn);
        gemm_bf<<<gF, 256, 0, stream>>>(hn, w1_bf + fo, b1 + l*FFDIM, nullptr, nullptr,
                                        nullptr, m1, M, FFDIM, DD, 1, 1, 1);
        // h_new = m1 @ w2^T + b2 + h2 + h   (== 2*h_old + attn + mlp)
        gemm_bf_s<<<gS, 256, 0, stream>>>(m1, w2_bf + fo, b2 + l*DD, h2, h,
                                          h, M, DD, FFDIM);
    }

    rmsnorm_kernel<<<M, 256, 0, stream>>>(h, lnd, hn);
    if (big_ws) {
        hipFuncSetAttribute((const void*)gemm256_bf,
                            hipFuncAttributeMaxDynamicSharedMemorySize, 131072);
        gemm256_bf<<<gV256, 512, 131072, stream>>>(hn, temb_bf, (float*)d_out,
                                                   M, NVOCAB);
    } else {
        gemm_bfw32<<<gVfb, 256, 0, stream>>>(hn, tok_emb, (float*)d_out, M, NVOCAB, DD);
    }
}